// Round 8
// baseline (9855.704 us; speedup 1.0000x reference)
//
#include <hip/hip_runtime.h>
#include <math.h>

typedef __attribute__((ext_vector_type(8))) _Float16 f16x8;
typedef __attribute__((ext_vector_type(4))) float f32x4;

__device__ __forceinline__ void f32_split(float x, ushort& h, ushort& l) {
    _Float16 hh = (_Float16)x;
    float r = x - (float)hh;
    _Float16 ll = (_Float16)r;
    union { _Float16 f; ushort u; } a, b;
    a.f = hh; b.f = ll;
    h = a.u; l = b.u;
}
__device__ __forceinline__ float h2f(ushort u) {
    union { ushort u; _Float16 f; } v; v.u = u; return (float)v.f;
}

// ---------------------------------------------------------------------------
// Weight transform: fp32 OIHW [CO][CI][3][3] -> f16 hi/lo tap-major [9][CO][CI]
// ---------------------------------------------------------------------------
__global__ void wtr_kernel(const float* __restrict__ src, ushort* __restrict__ dhi,
                           ushort* __restrict__ dlo, int CO, int CI)
{
    int n = CO * CI * 9, coci = CO * CI;
    for (int idx = blockIdx.x * 256 + threadIdx.x; idx < n; idx += gridDim.x * 256) {
        int tp = idx / coci, r = idx % coci;
        int co = r / CI, ci = r % CI;
        ushort h, l;
        f32_split(src[((size_t)co * CI + ci) * 9 + tp], h, l);
        dhi[idx] = h; dlo[idx] = l;
    }
}

// ---------------------------------------------------------------------------
// conv1a (1->64, 3x3) from fp32 image, f16 hi/lo split NHWC band output.
// ---------------------------------------------------------------------------
__global__ __launch_bounds__(256) void conv1a_kernel(
    const float* __restrict__ img, const float* __restrict__ w1a,
    const float* __restrict__ b1a, ushort* __restrict__ out, size_t opl,
    int iy0, int nr)
{
    __shared__ float wls[576];
    __shared__ float bls[64];
    int t = threadIdx.x;
    for (int i = t; i < 576; i += 256) wls[i] = w1a[i];
    if (t < 64) bls[t] = b1a[t];
    __syncthreads();

    int gid = blockIdx.x * 256 + t;
    int grp = gid & 7;
    int px = gid >> 3;
    int col = px % 640;
    int rest = px / 640;
    int rr = rest % nr;
    int b = rest / nr;
    int gy = iy0 + rr;

    float a[8];
    #pragma unroll
    for (int j = 0; j < 8; ++j) a[j] = bls[grp * 8 + j];
    #pragma unroll
    for (int ky = 0; ky < 3; ++ky) {
        int y = gy + ky - 1;
        if (y < 0 || y >= 480) continue;
        #pragma unroll
        for (int kx = 0; kx < 3; ++kx) {
            int x = col + kx - 1;
            if (x < 0 || x >= 640) continue;
            float iv = img[((size_t)b * 480 + y) * 640 + x];
            #pragma unroll
            for (int j = 0; j < 8; ++j)
                a[j] = fmaf(iv, wls[(grp * 8 + j) * 9 + ky * 3 + kx], a[j]);
        }
    }
    union { ushort u[8]; int4 v; } hs, ls;
    #pragma unroll
    for (int j = 0; j < 8; ++j) {
        float v = fmaxf(a[j], 0.f);
        f32_split(v, hs.u[j], ls.u[j]);
    }
    size_t oa = (((size_t)b * nr + rr) * 640 + col) * 64 + grp * 8;
    *reinterpret_cast<int4*>(&out[oa]) = hs.v;
    *reinterpret_cast<int4*>(&out[oa + opl]) = ls.v;
}

// ---------------------------------------------------------------------------
// Split-f16 MFMA implicit-GEMM conv3x3 + relu (+pool), v4 two-pass schedule.
// Block: (MW*8 rows x 8 cols) px x (NW*NR*16) out-ch; MW*NW waves.
// Wave: 64 px x (16*NR) co. A staged ONE PLANE at a time in LDS:
//   pass 0: hi plane -> ah*wh + ah*wl ; pass 1: lo plane -> al*wh.
// LDS layout: pitch 64 ushorts, 16B slot XOR-swizzled by (row&7):
//   conflict-free, all reads single aligned ds_read_b128.
// W read per-lane from global (L2-resident). No barriers inside tap loop.
// ---------------------------------------------------------------------------
template<int CI, int MW, int NW, int NR, bool POOL>
__global__ __launch_bounds__(MW * NW * 64, 4) void mconv3_kernel(
    const ushort* __restrict__ in, size_t ipl,
    const ushort* __restrict__ whi, const ushort* __restrict__ wlo, // [9][COT][CI]
    const float* __restrict__ bias,
    ushort* __restrict__ out, size_t opl,
    int H, int W, int COT, int TXC,
    int iy0, int inr, int y_start, int y_lim, int oy0, int onr)
{
    constexpr int BS = MW * NW * 64;
    constexpr int HALO = (MW * 8 + 2) * 10;          // 180 for MW=2
    __shared__ __align__(16) ushort A[HALO * 64];    // one plane, swizzled

    int t = threadIdx.x;
    int tx = blockIdx.x % TXC, ty = blockIdx.x / TXC;
    int x0 = tx * 8, y0 = y_start + ty * (MW * 8);
    int co0 = blockIdx.y * (NW * NR * 16);
    int b = blockIdx.z;

    int lane = t & 63, wid = t >> 6;
    int wm = wid / NW, wn = wid % NW;
    int fr = lane & 15, fg = lane >> 4;

    int hpx[4];
    #pragma unroll
    for (int mi = 0; mi < 4; ++mi) {
        int p = wm * 64 + mi * 16 + fr;
        hpx[mi] = (p >> 3) * 10 + (p & 7);
    }
    size_t wro[NR];
    #pragma unroll
    for (int nj = 0; nj < NR; ++nj) {
        int cog = co0 + wn * NR * 16 + nj * 16 + fr;
        wro[nj] = (size_t)cog * CI + fg * 8;
    }

    f32x4 acc[4][NR];
    #pragma unroll
    for (int nj = 0; nj < NR; ++nj) {
        float bv = bias[co0 + wn * NR * 16 + nj * 16 + fr];
        #pragma unroll
        for (int mi = 0; mi < 4; ++mi)
            acc[mi][nj] = f32x4{bv, bv, bv, bv};
    }

    const int NC = CI / 64;
    for (int cc = 0; cc < NC; ++cc) {
        for (int pass = 0; pass < 2; ++pass) {
            if (cc > 0 || pass > 0) __syncthreads();   // readers done with A
            size_t poff = pass ? ipl : 0;
            // ---- stage one plane (HALO px x 64 ch), swizzled write ----
            for (int idx = t; idx < HALO * 8; idx += BS) {
                int hp = idx >> 3, c8 = idx & 7;
                int hy = y0 - 1 + hp / 10, hx = x0 - 1 + hp % 10;
                int4 v = make_int4(0, 0, 0, 0);
                if (hy >= iy0 && hy < iy0 + inr && hx >= 0 && hx < W) {
                    size_t a = (((size_t)b * inr + (hy - iy0)) * W + hx) * CI
                               + cc * 64 + c8 * 8 + poff;
                    v = *reinterpret_cast<const int4*>(&in[a]);
                }
                *reinterpret_cast<int4*>(&A[hp * 64 + ((c8 ^ (hp & 7)) << 3)]) = v;
            }
            __syncthreads();

            // ---- 9 taps x 2 k-chunks, barrier-free ----
            #pragma unroll 1
            for (int tap = 0; tap < 9; ++tap) {
                const ushort* wtH = whi + (size_t)tap * COT * CI + cc * 64;
                const ushort* wtL = wlo + (size_t)tap * COT * CI + cc * 64;
                f16x8 wh[2][NR], wl[2][NR];
                #pragma unroll
                for (int kc = 0; kc < 2; ++kc)
                    #pragma unroll
                    for (int nj = 0; nj < NR; ++nj) {
                        wh[kc][nj] = *reinterpret_cast<const f16x8*>(&wtH[wro[nj] + kc * 32]);
                        if (pass == 0)
                            wl[kc][nj] = *reinterpret_cast<const f16x8*>(&wtL[wro[nj] + kc * 32]);
                    }
                int ky = tap / 3, kx = tap - ky * 3;
                #pragma unroll
                for (int kc = 0; kc < 2; ++kc) {
                    f16x8 av[4];
                    #pragma unroll
                    for (int mi = 0; mi < 4; ++mi) {
                        int hp = hpx[mi] + ky * 10 + kx;
                        int slot = (kc * 4 + fg) ^ (hp & 7);
                        av[mi] = *reinterpret_cast<const f16x8*>(&A[hp * 64 + slot * 8]);
                    }
                    #pragma unroll
                    for (int mi = 0; mi < 4; ++mi)
                        #pragma unroll
                        for (int nj = 0; nj < NR; ++nj) {
                            acc[mi][nj] = __builtin_amdgcn_mfma_f32_16x16x32_f16(
                                av[mi], wh[kc][nj], acc[mi][nj], 0, 0, 0);
                            if (pass == 0)
                                acc[mi][nj] = __builtin_amdgcn_mfma_f32_16x16x32_f16(
                                    av[mi], wl[kc][nj], acc[mi][nj], 0, 0, 0);
                        }
                }
            }
        }
    }

    // ---- epilogue ----
    if constexpr (POOL) {
        // px: y = wm*8+mi*2+(fg>>1), x = (fg&1)*4+r. pairs: x^1=r^1, y^1=fg^2(lane^32)
        int Wp = W >> 1;
        #pragma unroll
        for (int mi = 0; mi < 4; ++mi) {
            int qy = (y0 >> 1) + wm * 4 + mi;
            #pragma unroll
            for (int nj = 0; nj < NR; ++nj) {
                f32x4 v = acc[mi][nj];
                float v0 = fmaxf(v[0], 0.f), v1 = fmaxf(v[1], 0.f);
                float v2 = fmaxf(v[2], 0.f), v3 = fmaxf(v[3], 0.f);
                float mA = fmaxf(v0, v1), mB = fmaxf(v2, v3);
                float pA = fmaxf(mA, __shfl_xor(mA, 32));
                float pB = fmaxf(mB, __shfl_xor(mB, 32));
                if ((fg & 2) == 0 && qy < y_lim) {
                    int qx = (x0 >> 1) + (fg & 1) * 2;
                    int cog = co0 + wn * NR * 16 + nj * 16 + fr;
                    size_t oa = (((size_t)b * onr + (qy - oy0)) * Wp + qx) * COT + cog;
                    ushort h, l;
                    f32_split(pA, h, l);
                    out[oa] = h; out[oa + opl] = l;
                    f32_split(pB, h, l);
                    out[oa + COT] = h; out[oa + COT + opl] = l;
                }
            }
        }
    } else {
        #pragma unroll
        for (int mi = 0; mi < 4; ++mi)
            #pragma unroll
            for (int r = 0; r < 4; ++r) {
                int gy = y0 + wm * 8 + mi * 2 + (fg >> 1);
                int gx = x0 + (fg & 1) * 4 + r;
                if (gy < y_lim) {
                    size_t base = (((size_t)b * onr + (gy - oy0)) * W + gx) * COT;
                    #pragma unroll
                    for (int nj = 0; nj < NR; ++nj) {
                        int cog = co0 + wn * NR * 16 + nj * 16 + fr;
                        ushort h, l;
                        f32_split(fmaxf(acc[mi][nj][r], 0.f), h, l);
                        out[base + cog] = h;
                        out[base + cog + opl] = l;
                    }
                }
            }
    }
}

// ---------------------------------------------------------------------------
// Detector head: 1x1 conv (256->65) + softmax(65) + dustbin drop + pixel
// shuffle to [8,480,640]. cpa = f16 hi/lo planes [38400][256]. Wave per pixel.
// ---------------------------------------------------------------------------
__global__ __launch_bounds__(256) void scores_kernel(
    const ushort* __restrict__ cpa, size_t cpl, const float* __restrict__ wpb,
    const float* __restrict__ bpb, float* __restrict__ sc)
{
    __shared__ __align__(16) float wT[128][66];
    __shared__ __align__(16) float xs[4][256];
    int t = threadIdx.x;
    int wave = t >> 6, lane = t & 63;
    int p = blockIdx.x * 4 + wave;

    ushort4 xh = *reinterpret_cast<const ushort4*>(&cpa[(size_t)p * 256 + lane * 4]);
    ushort4 xl = *reinterpret_cast<const ushort4*>(&cpa[(size_t)p * 256 + lane * 4 + cpl]);
    xs[wave][lane * 4 + 0] = h2f(xh.x) + h2f(xl.x);
    xs[wave][lane * 4 + 1] = h2f(xh.y) + h2f(xl.y);
    xs[wave][lane * 4 + 2] = h2f(xh.z) + h2f(xl.z);
    xs[wave][lane * 4 + 3] = h2f(xh.w) + h2f(xl.w);

    float a = bpb[lane];
    float a2 = bpb[64];
    for (int k0 = 0; k0 < 256; k0 += 128) {
        __syncthreads();
        for (int idx = t; idx < 65 * 128; idx += 256) {
            int o = idx / 128, i = idx % 128;
            wT[i][o] = wpb[o * 256 + k0 + i];
        }
        __syncthreads();
        for (int i = 0; i < 128; ++i) {
            float xb = xs[wave][k0 + i];
            a  = fmaf(xb, wT[i][lane], a);
            a2 = fmaf(xb, wT[i][64], a2);
        }
    }
    float m = a;
    #pragma unroll
    for (int off = 32; off; off >>= 1) m = fmaxf(m, __shfl_xor(m, off));
    m = fmaxf(m, a2);
    float e = expf(a - m);
    float s = e;
    #pragma unroll
    for (int off = 32; off; off >>= 1) s += __shfl_xor(s, off);
    s += expf(a2 - m);
    float r = e / s;
    int b = p / 4800, hw = p % 4800, h = hw / 80, w = hw % 80;
    int rr = lane >> 3, cc = lane & 7;
    sc[b * 307200 + (h * 8 + rr) * 640 + (w * 8 + cc)] = r;
}

// ---------------------------------------------------------------------------
// NMS: 16x16 tile + radius-3 halo, 7x7 max with -inf padding. (fp32)
// ---------------------------------------------------------------------------
#define NMS_STAGE(SRC)                                                        \
    __shared__ float ts[22][23];                                              \
    const int H = 480, W = 640;                                               \
    int bx = blockIdx.x * 16, by = blockIdx.y * 16, b = blockIdx.z;           \
    int t = threadIdx.x;                                                      \
    for (int idx = t; idx < 22 * 22; idx += 256) {                            \
        int yy = idx / 22, xx = idx % 22;                                     \
        int gy = by + yy - 3, gx = bx + xx - 3;                               \
        ts[yy][xx] = (gy >= 0 && gy < H && gx >= 0 && gx < W)                 \
                         ? (SRC)[b * 307200 + gy * W + gx] : -INFINITY;       \
    }                                                                         \
    __syncthreads();                                                          \
    int lx = t & 15, ly = t >> 4;                                             \
    float mx = -INFINITY;                                                     \
    _Pragma("unroll")                                                         \
    for (int dy = 0; dy < 7; ++dy)                                            \
        _Pragma("unroll")                                                     \
        for (int dx = 0; dx < 7; ++dx)                                       \
            mx = fmaxf(mx, ts[ly + dy][lx + dx]);                            \
    int p = b * 307200 + (by + ly) * W + (bx + lx);

__global__ __launch_bounds__(256) void nms_max_mask(
    const float* __restrict__ s, float* __restrict__ M)
{
    NMS_STAGE(s)
    M[p] = (ts[ly + 3][lx + 3] == mx) ? 1.f : 0.f;
}

__global__ __launch_bounds__(256) void nms_supp(
    const float* __restrict__ M, const float* __restrict__ s,
    float* __restrict__ supp, float* __restrict__ ss)
{
    NMS_STAGE(M)
    float sup = (mx > 0.f) ? 1.f : 0.f;
    supp[p] = sup;
    ss[p] = (sup > 0.f) ? 0.f : s[p];
}

template<bool LAST>
__global__ __launch_bounds__(256) void nms_update(
    const float* __restrict__ ssb, const float* __restrict__ supp,
    const float* __restrict__ s, float* __restrict__ M, float* __restrict__ outp)
{
    NMS_STAGE(ssb)
    bool new_max = (ts[ly + 3][lx + 3] == mx);
    float mo = M[p];
    float sp = supp[p];
    bool mn = (mo > 0.f) || (new_max && sp == 0.f);
    if (LAST)
        outp[p] = mn ? s[p] : 0.f;
    else
        M[p] = mn ? 1.f : 0.f;
}

// ---------------------------------------------------------------------------
// Descriptor head: 1x1 conv (256->256) + bias + per-pixel L2 normalize.
// f16 hi/lo NHWC input [38400][256] -> NCHW fp32 output [8][256][4800].
// ---------------------------------------------------------------------------
__global__ __launch_bounds__(256, 2) void descdb_kernel(
    const ushort* __restrict__ cda, size_t cpl, const float* __restrict__ wdb,
    const float* __restrict__ bdb, float* __restrict__ outp)
{
    __shared__ __align__(16) float Xs[16][65];
    __shared__ __align__(16) float Ws[16][257];
    int t = threadIdx.x;
    int m0 = blockIdx.x * 64;
    int n_id = t & 31, m_id = t >> 5;

    float acc[8][8];
    #pragma unroll
    for (int nn = 0; nn < 8; ++nn) {
        float bv = bdb[n_id + 32 * nn];
        #pragma unroll
        for (int mm = 0; mm < 8; ++mm) acc[mm][nn] = bv;
    }

    for (int k0 = 0; k0 < 256; k0 += 16) {
        __syncthreads();
        for (int idx = t; idx < 64 * 16; idx += 256) {
            int m = idx / 16, k = idx % 16;
            size_t a = (size_t)(m0 + m) * 256 + k0 + k;
            Xs[k][m] = h2f(cda[a]) + h2f(cda[a + cpl]);
        }
        for (int idx = t; idx < 256 * 16; idx += 256) {
            int o = idx / 16, k = idx % 16;
            Ws[k][o] = wdb[o * 256 + k0 + k];
        }
        __syncthreads();
        #pragma unroll
        for (int k = 0; k < 16; ++k) {
            float xv[8], wv[8];
            #pragma unroll
            for (int mm = 0; mm < 8; ++mm) xv[mm] = Xs[k][m_id * 8 + mm];
            #pragma unroll
            for (int nn = 0; nn < 8; ++nn) wv[nn] = Ws[k][n_id + 32 * nn];
            #pragma unroll
            for (int mm = 0; mm < 8; ++mm)
                #pragma unroll
                for (int nn = 0; nn < 8; ++nn)
                    acc[mm][nn] = fmaf(xv[mm], wv[nn], acc[mm][nn]);
        }
    }
    #pragma unroll
    for (int mm = 0; mm < 8; ++mm) {
        float sq = 0.f;
        #pragma unroll
        for (int nn = 0; nn < 8; ++nn) sq = fmaf(acc[mm][nn], acc[mm][nn], sq);
        #pragma unroll
        for (int off = 16; off; off >>= 1) sq += __shfl_xor(sq, off);
        float inv = 1.f / sqrtf(sq);
        int P = m0 + m_id * 8 + mm;
        int b = P / 4800, hw = P % 4800;
        #pragma unroll
        for (int nn = 0; nn < 8; ++nn) {
            int o = n_id + 32 * nn;
            outp[(b * 256 + o) * 4800 + hw] = acc[mm][nn] * inv;
        }
    }
}

// ---------------------------------------------------------------------------
extern "C" void kernel_launch(void* const* d_in, const int* in_sizes, int n_in,
                              void* d_out, int out_size, void* d_ws, size_t ws_size,
                              hipStream_t stream)
{
    const float* image = (const float*)d_in[0];
    const float* w1a = (const float*)d_in[1];  const float* b1a = (const float*)d_in[2];
    const float* w1b = (const float*)d_in[3];  const float* b1b = (const float*)d_in[4];
    const float* w2a = (const float*)d_in[5];  const float* b2a = (const float*)d_in[6];
    const float* w2b = (const float*)d_in[7];  const float* b2b = (const float*)d_in[8];
    const float* w3a = (const float*)d_in[9];  const float* b3a = (const float*)d_in[10];
    const float* w3b = (const float*)d_in[11]; const float* b3b = (const float*)d_in[12];
    const float* w4a = (const float*)d_in[13]; const float* b4a = (const float*)d_in[14];
    const float* w4b = (const float*)d_in[15]; const float* b4b = (const float*)d_in[16];
    const float* wPa = (const float*)d_in[17]; const float* bPa = (const float*)d_in[18];
    const float* wPb = (const float*)d_in[19]; const float* bPb = (const float*)d_in[20];
    const float* wDa = (const float*)d_in[21]; const float* bDa = (const float*)d_in[22];
    const float* wDb = (const float*)d_in[23]; const float* bDb = (const float*)d_in[24];

    float* out_sc   = (float*)d_out;            // [8,480,640]
    float* out_nms  = out_sc + 2457600;         // [8,480,640]
    float* out_desc = out_sc + 4915200;         // [8,256,60,80]

    ushort* U = (ushort*)d_ws;
    const int O1B = 0, O2A = 36864, O2B = 73728, O3A = 110592, O3B = 184320,
              O4A = 331776, O4B = 479232, OPA = 626688, ODA = 921600;
    const size_t TOT = 1216512;
    ushort* Whi = U;
    ushort* Wlo = U + TOT;
    ushort* C1A = U + 2500000;    // conv1a band: 2 x (8*<=90*640*64)
    ushort* A1b = U + 62000000;   // conv1 out band
    ushort* A2b = U + 76500000;   // conv2a out band
    ushort* A3  = U + 90500000;   // [8,120,160,64]  2 x 9,830,400
    ushort* A4  = U + 2500000;    // [8,120,160,128] 2 x 19,660,800
    ushort* A5  = U + 62000000;   // [8,60,80,128]   2 x 4,915,200
    ushort* A6  = U + 42000000;   // [8,60,80,128]
    ushort* A7  = U + 52000000;   // [8,60,80,128]
    ushort* cPa = U + 72000000;   // [8,60,80,256]   2 x 9,830,400
    ushort* cDa = U + 72000000;
    float* nmsMb  = (float*)(U + 92000000);
    float* nmsSup = nmsMb + 2457600;
    float* nmsSs  = nmsSup + 2457600;

    struct WE { const float* w; int off, co, ci; };
    WE WL[9] = {{w1b, O1B, 64, 64},  {w2a, O2A, 64, 64},  {w2b, O2B, 64, 64},
                {w3a, O3A, 128, 64}, {w3b, O3B, 128, 128},{w4a, O4A, 128, 128},
                {w4b, O4B, 128, 128},{wPa, OPA, 256, 128},{wDa, ODA, 256, 128}};
    for (int i = 0; i < 9; ++i) {
        int n = WL[i].co * WL[i].ci * 9;
        wtr_kernel<<<(n + 255) / 256, 256, 0, stream>>>(
            WL[i].w, Whi + WL[i].off, Wlo + WL[i].off, WL[i].co, WL[i].ci);
    }

    const size_t P3 = 9830400, P4 = 19660800, P5 = 4915200, PP = 9830400;

    // --- stage 1+2 striped (S=40 pooled rows, 6 stripes) ---
    for (int r0 = 0; r0 < 240; r0 += 40) {
        int r1 = r0 + 40;
        int a0 = r0 - 2 < 0 ? 0 : r0 - 2, a1 = r1 + 2 > 240 ? 240 : r1 + 2;
        int anr = a1 - a0;
        int iy0c = 2 * a0 - 1 < 0 ? 0 : 2 * a0 - 1;
        int iy1c = 2 * a1 + 1 > 480 ? 480 : 2 * a1 + 1;
        int n1a = iy1c - iy0c;
        size_t PC = (size_t)8 * n1a * 640 * 64;
        conv1a_kernel<<<n1a * 160, 256, 0, stream>>>(image, w1a, b1a, C1A, PC, iy0c, n1a);

        size_t P1 = (size_t)8 * anr * 320 * 64;
        int ty1 = (2 * anr + 15) / 16;
        mconv3_kernel<64, 2, 1, 4, true><<<dim3(80 * ty1, 1, 8), 128, 0, stream>>>(
            C1A, PC, Whi + O1B, Wlo + O1B, b1b,
            A1b, P1, 480, 640, 64, 80, iy0c, n1a, 2 * a0, a1, a0, anr);

        int c0 = r0 - 1 < 0 ? 0 : r0 - 1, c1 = r1 + 1 > 240 ? 240 : r1 + 1;
        int cnr = c1 - c0;
        size_t P2 = (size_t)8 * cnr * 320 * 64;
        int ty2 = (cnr + 15) / 16;
        mconv3_kernel<64, 2, 1, 4, false><<<dim3(40 * ty2, 1, 8), 128, 0, stream>>>(
            A1b, P1, Whi + O2A, Wlo + O2A, b2a,
            A2b, P2, 240, 320, 64, 40, a0, anr, c0, c1, c0, cnr);

        int ty3 = (40 + 15) / 16;
        mconv3_kernel<64, 2, 1, 4, true><<<dim3(40 * ty3, 1, 8), 128, 0, stream>>>(
            A2b, P2, Whi + O2B, Wlo + O2B, b2b,
            A3, P3, 240, 320, 64, 40, c0, cnr, r0, r1 >> 1, 0, 120);
    }

    // --- stage 3 (full) ---
    mconv3_kernel<64, 2, 2, 4, false><<<dim3(20 * 8, 1, 8), 256, 0, stream>>>(
        A3, P3, Whi + O3A, Wlo + O3A, b3a,
        A4, P4, 120, 160, 128, 20, 0, 120, 0, 120, 0, 120);
    mconv3_kernel<128, 2, 2, 4, true><<<dim3(20 * 8, 1, 8), 256, 0, stream>>>(
        A4, P4, Whi + O3B, Wlo + O3B, b3b,
        A5, P5, 120, 160, 128, 20, 0, 120, 0, 60, 0, 60);

    // --- stage 4 ---
    mconv3_kernel<128, 2, 2, 4, false><<<dim3(10 * 4, 1, 8), 256, 0, stream>>>(
        A5, P5, Whi + O4A, Wlo + O4A, b4a,
        A6, P5, 60, 80, 128, 10, 0, 60, 0, 60, 0, 60);
    mconv3_kernel<128, 2, 2, 4, false><<<dim3(10 * 4, 1, 8), 256, 0, stream>>>(
        A6, P5, Whi + O4B, Wlo + O4B, b4b,
        A7, P5, 60, 80, 128, 10, 0, 60, 0, 60, 0, 60);

    // --- detector head ---
    mconv3_kernel<128, 2, 2, 4, false><<<dim3(10 * 4, 2, 8), 256, 0, stream>>>(
        A7, P5, Whi + OPA, Wlo + OPA, bPa,
        cPa, PP, 60, 80, 256, 10, 0, 60, 0, 60, 0, 60);
    scores_kernel<<<9600, 256, 0, stream>>>(cPa, PP, wPb, bPb, out_sc);

    // --- NMS (radius 3, 2 rounds) ---
    nms_max_mask<<<dim3(40, 30, 8), 256, 0, stream>>>(out_sc, nmsMb);
    nms_supp<<<dim3(40, 30, 8), 256, 0, stream>>>(nmsMb, out_sc, nmsSup, nmsSs);
    nms_update<false><<<dim3(40, 30, 8), 256, 0, stream>>>(nmsSs, nmsSup, out_sc, nmsMb, out_nms);
    nms_supp<<<dim3(40, 30, 8), 256, 0, stream>>>(nmsMb, out_sc, nmsSup, nmsSs);
    nms_update<true><<<dim3(40, 30, 8), 256, 0, stream>>>(nmsSs, nmsSup, out_sc, nmsMb, out_nms);

    // --- descriptor head ---
    mconv3_kernel<128, 2, 2, 4, false><<<dim3(10 * 4, 2, 8), 256, 0, stream>>>(
        A7, P5, Whi + ODA, Wlo + ODA, bDa,
        cDa, PP, 60, 80, 256, 10, 0, 60, 0, 60, 0, 60);
    descdb_kernel<<<600, 256, 0, stream>>>(cDa, PP, wDb, bDb, out_desc);
}

// Round 9
// 2790.350 us; speedup vs baseline: 3.5321x; 3.5321x over previous
//
#include <hip/hip_runtime.h>
#include <math.h>

typedef __attribute__((ext_vector_type(8))) _Float16 f16x8;
typedef __attribute__((ext_vector_type(4))) float f32x4;

__device__ __forceinline__ void f32_split(float x, ushort& h, ushort& l) {
    _Float16 hh = (_Float16)x;
    float r = x - (float)hh;
    _Float16 ll = (_Float16)r;
    union { _Float16 f; ushort u; } a, b;
    a.f = hh; b.f = ll;
    h = a.u; l = b.u;
}
__device__ __forceinline__ float h2f(ushort u) {
    union { ushort u; _Float16 f; } v; v.u = u; return (float)v.f;
}

// ---------------------------------------------------------------------------
// Weight transform: fp32 OIHW [CO][CI][3][3] -> f16 hi/lo tap-major [9][CO][CI]
// ---------------------------------------------------------------------------
__global__ void wtr_kernel(const float* __restrict__ src, ushort* __restrict__ dhi,
                           ushort* __restrict__ dlo, int CO, int CI)
{
    int n = CO * CI * 9, coci = CO * CI;
    for (int idx = blockIdx.x * 256 + threadIdx.x; idx < n; idx += gridDim.x * 256) {
        int tp = idx / coci, r = idx % coci;
        int co = r / CI, ci = r % CI;
        ushort h, l;
        f32_split(src[((size_t)co * CI + ci) * 9 + tp], h, l);
        dhi[idx] = h; dlo[idx] = l;
    }
}

// ---------------------------------------------------------------------------
// Split-f16 MFMA implicit-GEMM conv3x3 + relu (+pool), v5.
// Round-6 architecture (fused conv1a, single-pass hi+lo LDS staging,
// barrier-free tap loop, weights per-lane from global/L2) with:
//  - pitch-64 XOR-swizzled LDS (single aligned ds_read_b128, conflict-free)
//  - MW/NW/NR tiling (wave = 64 px x 16*NR co)
// Product = 3 MFMAs: ah*wh + al*wh + ah*wl (fp32 accumulate).
// ---------------------------------------------------------------------------
template<int CI, int MW, int NW, int NR, bool POOL, bool FUSE1A>
__global__ __launch_bounds__(MW * NW * 64, 2) void mconv4_kernel(
    const ushort* __restrict__ in, size_t ipl,
    const float* __restrict__ image, const float* __restrict__ w1a,
    const float* __restrict__ b1a,
    const ushort* __restrict__ whi, const ushort* __restrict__ wlo, // [9][COT][CI]
    const float* __restrict__ bias,
    ushort* __restrict__ out, size_t opl,
    int H, int W, int COT, int TXC,
    int iy0, int inr, int y_start, int y_lim, int oy0, int onr)
{
    constexpr int BS = MW * NW * 64;
    constexpr int HALO = (MW * 8 + 2) * 10;          // 180 for MW=2
    __shared__ __align__(16) ushort AHI[HALO * 64];
    __shared__ __align__(16) ushort ALO[HALO * 64];
    __shared__ float fshared[FUSE1A ? 880 : 4];

    int t = threadIdx.x;
    int tx = blockIdx.x % TXC, ty = blockIdx.x / TXC;
    int x0 = tx * 8, y0 = y_start + ty * (MW * 8);
    int co0 = blockIdx.y * (NW * NR * 16);
    int b = blockIdx.z;

    int lane = t & 63, wid = t >> 6;
    int wm = wid / NW, wn = wid % NW;
    int fr = lane & 15, fg = lane >> 4;

    int hpx[4];
    #pragma unroll
    for (int mi = 0; mi < 4; ++mi) {
        int p = wm * 64 + mi * 16 + fr;
        hpx[mi] = (p >> 3) * 10 + (p & 7);
    }
    size_t wro[NR];
    #pragma unroll
    for (int nj = 0; nj < NR; ++nj) {
        int cog = co0 + wn * NR * 16 + nj * 16 + fr;
        wro[nj] = (size_t)cog * CI + fg * 8;
    }

    f32x4 acc[4][NR];
    #pragma unroll
    for (int nj = 0; nj < NR; ++nj) {
        float bv = bias[co0 + wn * NR * 16 + nj * 16 + fr];
        #pragma unroll
        for (int mi = 0; mi < 4; ++mi)
            acc[mi][nj] = f32x4{bv, bv, bv, bv};
    }

    const int NC = CI / 64;
    for (int cc = 0; cc < NC; ++cc) {
        if (cc > 0) __syncthreads();
        // ---- stage A chunk (HALO px x 64 ch, hi+lo, swizzled) ----
        if constexpr (FUSE1A) {
            float* img_s = fshared;          // (MW*8+4) x 12 = 240 for MW=2
            float* w1a_s = fshared + 240;    // 576
            float* b1a_s = fshared + 816;    // 64
            for (int idx = t; idx < 240; idx += BS) {
                int iy = idx / 12, ix = idx % 12;
                int gy = y0 - 2 + iy, gx = x0 - 2 + ix;
                img_s[idx] = (gy >= 0 && gy < H && gx >= 0 && gx < W)
                                 ? image[((size_t)b * H + gy) * W + gx] : 0.f;
            }
            for (int idx = t; idx < 576; idx += BS) w1a_s[idx] = w1a[idx];
            if (t < 64) b1a_s[t] = b1a[t];
            __syncthreads();
            for (int idx = t; idx < HALO * 64; idx += BS) {
                int hp = idx >> 6, c = idx & 63;
                int hpy = hp / 10, hpx2 = hp % 10;
                int gy = y0 - 1 + hpy, gx = x0 - 1 + hpx2;
                float v = 0.f;
                if (gy >= 0 && gy < H && gx >= 0 && gx < W) {
                    float s = b1a_s[c];
                    #pragma unroll
                    for (int ky = 0; ky < 3; ++ky)
                        #pragma unroll
                        for (int kx = 0; kx < 3; ++kx)
                            s = fmaf(img_s[(hpy + ky) * 12 + hpx2 + kx],
                                     w1a_s[c * 9 + ky * 3 + kx], s);
                    v = fmaxf(s, 0.f);
                }
                ushort h, l; f32_split(v, h, l);
                int base = hp * 64 + ((((c >> 3) ^ (hp & 7))) << 3) + (c & 7);
                AHI[base] = h;
                ALO[base] = l;
            }
        } else {
            for (int idx = t; idx < HALO * 8; idx += BS) {
                int hp = idx >> 3, c8 = idx & 7;
                int hy = y0 - 1 + hp / 10, hx = x0 - 1 + hp % 10;
                int4 vh = make_int4(0, 0, 0, 0), vl = make_int4(0, 0, 0, 0);
                if (hy >= iy0 && hy < iy0 + inr && hx >= 0 && hx < W) {
                    size_t a = (((size_t)b * inr + (hy - iy0)) * W + hx) * CI + cc * 64 + c8 * 8;
                    vh = *reinterpret_cast<const int4*>(&in[a]);
                    vl = *reinterpret_cast<const int4*>(&in[a + ipl]);
                }
                int base = hp * 64 + ((c8 ^ (hp & 7)) << 3);
                *reinterpret_cast<int4*>(&AHI[base]) = vh;
                *reinterpret_cast<int4*>(&ALO[base]) = vl;
            }
        }
        __syncthreads();

        // ---- K-loop: 9 taps x 2 k-chunks, barrier-free ----
        #pragma unroll 1
        for (int tap = 0; tap < 9; ++tap) {
            const ushort* wtH = whi + (size_t)tap * COT * CI + cc * 64;
            const ushort* wtL = wlo + (size_t)tap * COT * CI + cc * 64;
            f16x8 wh[2][NR], wl[2][NR];
            #pragma unroll
            for (int kc = 0; kc < 2; ++kc)
                #pragma unroll
                for (int nj = 0; nj < NR; ++nj) {
                    wh[kc][nj] = *reinterpret_cast<const f16x8*>(&wtH[wro[nj] + kc * 32]);
                    wl[kc][nj] = *reinterpret_cast<const f16x8*>(&wtL[wro[nj] + kc * 32]);
                }
            int ky = tap / 3, kx = tap - ky * 3;
            #pragma unroll
            for (int kc = 0; kc < 2; ++kc) {
                f16x8 ah[4], al[4];
                #pragma unroll
                for (int mi = 0; mi < 4; ++mi) {
                    int hp = hpx[mi] + ky * 10 + kx;
                    int slot = (kc * 4 + fg) ^ (hp & 7);
                    ah[mi] = *reinterpret_cast<const f16x8*>(&AHI[hp * 64 + slot * 8]);
                    al[mi] = *reinterpret_cast<const f16x8*>(&ALO[hp * 64 + slot * 8]);
                }
                #pragma unroll
                for (int mi = 0; mi < 4; ++mi)
                    #pragma unroll
                    for (int nj = 0; nj < NR; ++nj) {
                        acc[mi][nj] = __builtin_amdgcn_mfma_f32_16x16x32_f16(
                            ah[mi], wh[kc][nj], acc[mi][nj], 0, 0, 0);
                        acc[mi][nj] = __builtin_amdgcn_mfma_f32_16x16x32_f16(
                            al[mi], wh[kc][nj], acc[mi][nj], 0, 0, 0);
                        acc[mi][nj] = __builtin_amdgcn_mfma_f32_16x16x32_f16(
                            ah[mi], wl[kc][nj], acc[mi][nj], 0, 0, 0);
                    }
            }
        }
    }

    // ---- epilogue ----
    if constexpr (POOL) {
        // px: y = wm*8+mi*2+(fg>>1), x = (fg&1)*4+r. pairs: x^1=r^1, y^1=fg^2(lane^32)
        int Wp = W >> 1;
        #pragma unroll
        for (int mi = 0; mi < 4; ++mi) {
            int qy = (y0 >> 1) + wm * 4 + mi;
            #pragma unroll
            for (int nj = 0; nj < NR; ++nj) {
                f32x4 v = acc[mi][nj];
                float v0 = fmaxf(v[0], 0.f), v1 = fmaxf(v[1], 0.f);
                float v2 = fmaxf(v[2], 0.f), v3 = fmaxf(v[3], 0.f);
                float mA = fmaxf(v0, v1), mB = fmaxf(v2, v3);
                float pA = fmaxf(mA, __shfl_xor(mA, 32));
                float pB = fmaxf(mB, __shfl_xor(mB, 32));
                if ((fg & 2) == 0 && qy < y_lim) {
                    int qx = (x0 >> 1) + (fg & 1) * 2;
                    int cog = co0 + wn * NR * 16 + nj * 16 + fr;
                    size_t oa = (((size_t)b * onr + (qy - oy0)) * Wp + qx) * COT + cog;
                    ushort h, l;
                    f32_split(pA, h, l);
                    out[oa] = h; out[oa + opl] = l;
                    f32_split(pB, h, l);
                    out[oa + COT] = h; out[oa + COT + opl] = l;
                }
            }
        }
    } else {
        #pragma unroll
        for (int mi = 0; mi < 4; ++mi)
            #pragma unroll
            for (int r = 0; r < 4; ++r) {
                int gy = y0 + wm * 8 + mi * 2 + (fg >> 1);
                int gx = x0 + (fg & 1) * 4 + r;
                if (gy < y_lim) {
                    size_t base = (((size_t)b * onr + (gy - oy0)) * W + gx) * COT;
                    #pragma unroll
                    for (int nj = 0; nj < NR; ++nj) {
                        int cog = co0 + wn * NR * 16 + nj * 16 + fr;
                        ushort h, l;
                        f32_split(fmaxf(acc[mi][nj][r], 0.f), h, l);
                        out[base + cog] = h;
                        out[base + cog + opl] = l;
                    }
                }
            }
    }
}

// ---------------------------------------------------------------------------
// Detector head: 1x1 conv (256->65) + softmax(65) + dustbin drop + pixel
// shuffle to [8,480,640]. cpa = f16 hi/lo planes [38400][256]. Wave per pixel.
// ---------------------------------------------------------------------------
__global__ __launch_bounds__(256) void scores_kernel(
    const ushort* __restrict__ cpa, size_t cpl, const float* __restrict__ wpb,
    const float* __restrict__ bpb, float* __restrict__ sc)
{
    __shared__ __align__(16) float wT[128][66];
    __shared__ __align__(16) float xs[4][256];
    int t = threadIdx.x;
    int wave = t >> 6, lane = t & 63;
    int p = blockIdx.x * 4 + wave;

    ushort4 xh = *reinterpret_cast<const ushort4*>(&cpa[(size_t)p * 256 + lane * 4]);
    ushort4 xl = *reinterpret_cast<const ushort4*>(&cpa[(size_t)p * 256 + lane * 4 + cpl]);
    xs[wave][lane * 4 + 0] = h2f(xh.x) + h2f(xl.x);
    xs[wave][lane * 4 + 1] = h2f(xh.y) + h2f(xl.y);
    xs[wave][lane * 4 + 2] = h2f(xh.z) + h2f(xl.z);
    xs[wave][lane * 4 + 3] = h2f(xh.w) + h2f(xl.w);

    float a = bpb[lane];
    float a2 = bpb[64];
    for (int k0 = 0; k0 < 256; k0 += 128) {
        __syncthreads();
        for (int idx = t; idx < 65 * 128; idx += 256) {
            int o = idx / 128, i = idx % 128;
            wT[i][o] = wpb[o * 256 + k0 + i];
        }
        __syncthreads();
        for (int i = 0; i < 128; ++i) {
            float xb = xs[wave][k0 + i];
            a  = fmaf(xb, wT[i][lane], a);
            a2 = fmaf(xb, wT[i][64], a2);
        }
    }
    float m = a;
    #pragma unroll
    for (int off = 32; off; off >>= 1) m = fmaxf(m, __shfl_xor(m, off));
    m = fmaxf(m, a2);
    float e = expf(a - m);
    float s = e;
    #pragma unroll
    for (int off = 32; off; off >>= 1) s += __shfl_xor(s, off);
    s += expf(a2 - m);
    float r = e / s;
    int b = p / 4800, hw = p % 4800, h = hw / 80, w = hw % 80;
    int rr = lane >> 3, cc = lane & 7;
    sc[b * 307200 + (h * 8 + rr) * 640 + (w * 8 + cc)] = r;
}

// ---------------------------------------------------------------------------
// NMS: 16x16 tile + radius-3 halo, 7x7 max with -inf padding. (fp32)
// ---------------------------------------------------------------------------
#define NMS_STAGE(SRC)                                                        \
    __shared__ float ts[22][23];                                              \
    const int H = 480, W = 640;                                               \
    int bx = blockIdx.x * 16, by = blockIdx.y * 16, b = blockIdx.z;           \
    int t = threadIdx.x;                                                      \
    for (int idx = t; idx < 22 * 22; idx += 256) {                            \
        int yy = idx / 22, xx = idx % 22;                                     \
        int gy = by + yy - 3, gx = bx + xx - 3;                               \
        ts[yy][xx] = (gy >= 0 && gy < H && gx >= 0 && gx < W)                 \
                         ? (SRC)[b * 307200 + gy * W + gx] : -INFINITY;       \
    }                                                                         \
    __syncthreads();                                                          \
    int lx = t & 15, ly = t >> 4;                                             \
    float mx = -INFINITY;                                                     \
    _Pragma("unroll")                                                         \
    for (int dy = 0; dy < 7; ++dy)                                            \
        _Pragma("unroll")                                                     \
        for (int dx = 0; dx < 7; ++dx)                                       \
            mx = fmaxf(mx, ts[ly + dy][lx + dx]);                            \
    int p = b * 307200 + (by + ly) * W + (bx + lx);

__global__ __launch_bounds__(256) void nms_max_mask(
    const float* __restrict__ s, float* __restrict__ M)
{
    NMS_STAGE(s)
    M[p] = (ts[ly + 3][lx + 3] == mx) ? 1.f : 0.f;
}

__global__ __launch_bounds__(256) void nms_supp(
    const float* __restrict__ M, const float* __restrict__ s,
    float* __restrict__ supp, float* __restrict__ ss)
{
    NMS_STAGE(M)
    float sup = (mx > 0.f) ? 1.f : 0.f;
    supp[p] = sup;
    ss[p] = (sup > 0.f) ? 0.f : s[p];
}

template<bool LAST>
__global__ __launch_bounds__(256) void nms_update(
    const float* __restrict__ ssb, const float* __restrict__ supp,
    const float* __restrict__ s, float* __restrict__ M, float* __restrict__ outp)
{
    NMS_STAGE(ssb)
    bool new_max = (ts[ly + 3][lx + 3] == mx);
    float mo = M[p];
    float sp = supp[p];
    bool mn = (mo > 0.f) || (new_max && sp == 0.f);
    if (LAST)
        outp[p] = mn ? s[p] : 0.f;
    else
        M[p] = mn ? 1.f : 0.f;
}

// ---------------------------------------------------------------------------
// Descriptor head: 1x1 conv (256->256) + bias + per-pixel L2 normalize.
// f16 hi/lo NHWC input [38400][256] -> NCHW fp32 output [8][256][4800].
// ---------------------------------------------------------------------------
__global__ __launch_bounds__(256, 2) void descdb_kernel(
    const ushort* __restrict__ cda, size_t cpl, const float* __restrict__ wdb,
    const float* __restrict__ bdb, float* __restrict__ outp)
{
    __shared__ __align__(16) float Xs[16][65];
    __shared__ __align__(16) float Ws[16][257];
    int t = threadIdx.x;
    int m0 = blockIdx.x * 64;
    int n_id = t & 31, m_id = t >> 5;

    float acc[8][8];
    #pragma unroll
    for (int nn = 0; nn < 8; ++nn) {
        float bv = bdb[n_id + 32 * nn];
        #pragma unroll
        for (int mm = 0; mm < 8; ++mm) acc[mm][nn] = bv;
    }

    for (int k0 = 0; k0 < 256; k0 += 16) {
        __syncthreads();
        for (int idx = t; idx < 64 * 16; idx += 256) {
            int m = idx / 16, k = idx % 16;
            size_t a = (size_t)(m0 + m) * 256 + k0 + k;
            Xs[k][m] = h2f(cda[a]) + h2f(cda[a + cpl]);
        }
        for (int idx = t; idx < 256 * 16; idx += 256) {
            int o = idx / 16, k = idx % 16;
            Ws[k][o] = wdb[o * 256 + k0 + k];
        }
        __syncthreads();
        #pragma unroll
        for (int k = 0; k < 16; ++k) {
            float xv[8], wv[8];
            #pragma unroll
            for (int mm = 0; mm < 8; ++mm) xv[mm] = Xs[k][m_id * 8 + mm];
            #pragma unroll
            for (int nn = 0; nn < 8; ++nn) wv[nn] = Ws[k][n_id + 32 * nn];
            #pragma unroll
            for (int mm = 0; mm < 8; ++mm)
                #pragma unroll
                for (int nn = 0; nn < 8; ++nn)
                    acc[mm][nn] = fmaf(xv[mm], wv[nn], acc[mm][nn]);
        }
    }
    #pragma unroll
    for (int mm = 0; mm < 8; ++mm) {
        float sq = 0.f;
        #pragma unroll
        for (int nn = 0; nn < 8; ++nn) sq = fmaf(acc[mm][nn], acc[mm][nn], sq);
        #pragma unroll
        for (int off = 16; off; off >>= 1) sq += __shfl_xor(sq, off);
        float inv = 1.f / sqrtf(sq);
        int P = m0 + m_id * 8 + mm;
        int b = P / 4800, hw = P % 4800;
        #pragma unroll
        for (int nn = 0; nn < 8; ++nn) {
            int o = n_id + 32 * nn;
            outp[(b * 256 + o) * 4800 + hw] = acc[mm][nn] * inv;
        }
    }
}

// ---------------------------------------------------------------------------
extern "C" void kernel_launch(void* const* d_in, const int* in_sizes, int n_in,
                              void* d_out, int out_size, void* d_ws, size_t ws_size,
                              hipStream_t stream)
{
    const float* image = (const float*)d_in[0];
    const float* w1a = (const float*)d_in[1];  const float* b1a = (const float*)d_in[2];
    const float* w1b = (const float*)d_in[3];  const float* b1b = (const float*)d_in[4];
    const float* w2a = (const float*)d_in[5];  const float* b2a = (const float*)d_in[6];
    const float* w2b = (const float*)d_in[7];  const float* b2b = (const float*)d_in[8];
    const float* w3a = (const float*)d_in[9];  const float* b3a = (const float*)d_in[10];
    const float* w3b = (const float*)d_in[11]; const float* b3b = (const float*)d_in[12];
    const float* w4a = (const float*)d_in[13]; const float* b4a = (const float*)d_in[14];
    const float* w4b = (const float*)d_in[15]; const float* b4b = (const float*)d_in[16];
    const float* wPa = (const float*)d_in[17]; const float* bPa = (const float*)d_in[18];
    const float* wPb = (const float*)d_in[19]; const float* bPb = (const float*)d_in[20];
    const float* wDa = (const float*)d_in[21]; const float* bDa = (const float*)d_in[22];
    const float* wDb = (const float*)d_in[23]; const float* bDb = (const float*)d_in[24];

    float* out_sc   = (float*)d_out;            // [8,480,640]
    float* out_nms  = out_sc + 2457600;         // [8,480,640]
    float* out_desc = out_sc + 4915200;         // [8,256,60,80]

    ushort* U = (ushort*)d_ws;
    const int O1B = 0, O2A = 36864, O2B = 73728, O3A = 110592, O3B = 184320,
              O4A = 331776, O4B = 479232, OPA = 626688, ODA = 921600;
    const size_t TOT = 1216512;
    ushort* Whi = U;
    ushort* Wlo = U + TOT;
    ushort* A1b = U + 62000000;   // conv1 out band (<=44 rows of 240-space)
    ushort* A2b = U + 76500000;   // conv2a out band (<=42 rows)
    ushort* A3  = U + 90500000;   // [8,120,160,64]  2 x 9,830,400
    ushort* A4  = U + 2500000;    // [8,120,160,128] 2 x 19,660,800
    ushort* A5  = U + 62000000;   // [8,60,80,128]   2 x 4,915,200
    ushort* A6  = U + 42000000;   // [8,60,80,128]
    ushort* A7  = U + 52000000;   // [8,60,80,128]
    ushort* cPa = U + 72000000;   // [8,60,80,256]   2 x 9,830,400
    ushort* cDa = U + 72000000;
    float* nmsMb  = (float*)(U + 92000000);
    float* nmsSup = nmsMb + 2457600;
    float* nmsSs  = nmsSup + 2457600;

    struct WE { const float* w; int off, co, ci; };
    WE WL[9] = {{w1b, O1B, 64, 64},  {w2a, O2A, 64, 64},  {w2b, O2B, 64, 64},
                {w3a, O3A, 128, 64}, {w3b, O3B, 128, 128},{w4a, O4A, 128, 128},
                {w4b, O4B, 128, 128},{wPa, OPA, 256, 128},{wDa, ODA, 256, 128}};
    for (int i = 0; i < 9; ++i) {
        int n = WL[i].co * WL[i].ci * 9;
        wtr_kernel<<<(n + 255) / 256, 256, 0, stream>>>(
            WL[i].w, Whi + WL[i].off, Wlo + WL[i].off, WL[i].co, WL[i].ci);
    }

    const size_t P3 = 9830400, P4 = 19660800, P5 = 4915200, PP = 9830400;

    // --- stage 1+2 striped (S=40 rows of conv2's 240-space, 6 stripes) ---
    for (int r0 = 0; r0 < 240; r0 += 40) {
        int r1 = r0 + 40;
        int a0 = r0 - 2 < 0 ? 0 : r0 - 2, a1 = r1 + 2 > 240 ? 240 : r1 + 2;
        int anr = a1 - a0;
        size_t P1 = (size_t)8 * anr * 320 * 64;
        int ty1 = (2 * anr + 15) / 16;
        // conv1a (fused) + conv1b + pool
        mconv4_kernel<64, 2, 2, 2, true, true><<<dim3(80 * ty1, 1, 8), 256, 0, stream>>>(
            nullptr, 0, image, w1a, b1a, Whi + O1B, Wlo + O1B, b1b,
            A1b, P1, 480, 640, 64, 80, 0, 480, 2 * a0, a1, a0, anr);

        int c0 = r0 - 1 < 0 ? 0 : r0 - 1, c1 = r1 + 1 > 240 ? 240 : r1 + 1;
        int cnr = c1 - c0;
        size_t P2 = (size_t)8 * cnr * 320 * 64;
        int ty2 = (cnr + 15) / 16;
        mconv4_kernel<64, 2, 1, 4, false, false><<<dim3(40 * ty2, 1, 8), 128, 0, stream>>>(
            A1b, P1, nullptr, nullptr, nullptr, Whi + O2A, Wlo + O2A, b2a,
            A2b, P2, 240, 320, 64, 40, a0, anr, c0, c1, c0, cnr);

        mconv4_kernel<64, 2, 1, 4, true, false><<<dim3(40 * 3, 1, 8), 128, 0, stream>>>(
            A2b, P2, nullptr, nullptr, nullptr, Whi + O2B, Wlo + O2B, b2b,
            A3, P3, 240, 320, 64, 40, c0, cnr, r0, r1 >> 1, 0, 120);
    }

    // --- stage 3 (full) ---
    mconv4_kernel<64, 2, 2, 4, false, false><<<dim3(20 * 8, 1, 8), 256, 0, stream>>>(
        A3, P3, nullptr, nullptr, nullptr, Whi + O3A, Wlo + O3A, b3a,
        A4, P4, 120, 160, 128, 20, 0, 120, 0, 120, 0, 120);
    mconv4_kernel<128, 2, 2, 4, true, false><<<dim3(20 * 8, 1, 8), 256, 0, stream>>>(
        A4, P4, nullptr, nullptr, nullptr, Whi + O3B, Wlo + O3B, b3b,
        A5, P5, 120, 160, 128, 20, 0, 120, 0, 60, 0, 60);

    // --- stage 4 ---
    mconv4_kernel<128, 2, 2, 4, false, false><<<dim3(10 * 4, 1, 8), 256, 0, stream>>>(
        A5, P5, nullptr, nullptr, nullptr, Whi + O4A, Wlo + O4A, b4a,
        A6, P5, 60, 80, 128, 10, 0, 60, 0, 60, 0, 60);
    mconv4_kernel<128, 2, 2, 4, false, false><<<dim3(10 * 4, 1, 8), 256, 0, stream>>>(
        A6, P5, nullptr, nullptr, nullptr, Whi + O4B, Wlo + O4B, b4b,
        A7, P5, 60, 80, 128, 10, 0, 60, 0, 60, 0, 60);

    // --- detector head ---
    mconv4_kernel<128, 2, 2, 4, false, false><<<dim3(10 * 4, 2, 8), 256, 0, stream>>>(
        A7, P5, nullptr, nullptr, nullptr, Whi + OPA, Wlo + OPA, bPa,
        cPa, PP, 60, 80, 256, 10, 0, 60, 0, 60, 0, 60);
    scores_kernel<<<9600, 256, 0, stream>>>(cPa, PP, wPb, bPb, out_sc);

    // --- NMS (radius 3, 2 rounds) ---
    nms_max_mask<<<dim3(40, 30, 8), 256, 0, stream>>>(out_sc, nmsMb);
    nms_supp<<<dim3(40, 30, 8), 256, 0, stream>>>(nmsMb, out_sc, nmsSup, nmsSs);
    nms_update<false><<<dim3(40, 30, 8), 256, 0, stream>>>(nmsSs, nmsSup, out_sc, nmsMb, out_nms);
    nms_supp<<<dim3(40, 30, 8), 256, 0, stream>>>(nmsMb, out_sc, nmsSup, nmsSs);
    nms_update<true><<<dim3(40, 30, 8), 256, 0, stream>>>(nmsSs, nmsSup, out_sc, nmsMb, out_nms);

    // --- descriptor head ---
    mconv4_kernel<128, 2, 2, 4, false, false><<<dim3(10 * 4, 2, 8), 256, 0, stream>>>(
        A7, P5, nullptr, nullptr, nullptr, Whi + ODA, Wlo + ODA, bDa,
        cDa, PP, 60, 80, 256, 10, 0, 60, 0, 60, 0, 60);
    descdb_kernel<<<600, 256, 0, stream>>>(cDa, PP, wDb, bDb, out_desc);
}

// Round 12
// 2777.150 us; speedup vs baseline: 3.5489x; 1.0048x over previous
//
#include <hip/hip_runtime.h>
#include <math.h>

typedef __attribute__((ext_vector_type(8))) _Float16 f16x8;
typedef __attribute__((ext_vector_type(4))) float f32x4;

__device__ __forceinline__ void f32_split(float x, ushort& h, ushort& l) {
    _Float16 hh = (_Float16)x;
    float r = x - (float)hh;
    _Float16 ll = (_Float16)r;
    union { _Float16 f; ushort u; } a, b;
    a.f = hh; b.f = ll;
    h = a.u; l = b.u;
}
__device__ __forceinline__ float h2f(ushort u) {
    union { ushort u; _Float16 f; } v; v.u = u; return (float)v.f;
}

// ---------------------------------------------------------------------------
// Weight transform: fp32 OIHW [CO][CI][3][3] -> f16 hi/lo tap-major [9][CO][CI]
// ---------------------------------------------------------------------------
__global__ void wtr_kernel(const float* __restrict__ src, ushort* __restrict__ dhi,
                           ushort* __restrict__ dlo, int CO, int CI)
{
    int n = CO * CI * 9, coci = CO * CI;
    for (int idx = blockIdx.x * 256 + threadIdx.x; idx < n; idx += gridDim.x * 256) {
        int tp = idx / coci, r = idx % coci;
        int co = r / CI, ci = r % CI;
        ushort h, l;
        f32_split(src[((size_t)co * CI + ci) * 9 + tp], h, l);
        dhi[idx] = h; dlo[idx] = l;
    }
}

// ---------------------------------------------------------------------------
// Split-f16 MFMA implicit-GEMM conv3x3 + relu (+pool), v6.
// v5 (fused conv1a, hi+lo LDS staging, swizzled pitch-64 LDS, per-lane L2
// weights) + software-pipelined weight loads: double register buffer at
// half-tap (kc) granularity -> L2 latency hidden under 48-MFMA clusters.
// Product = 3 MFMAs: ah*wh + al*wh + ah*wl (fp32 accumulate).
// ---------------------------------------------------------------------------
template<int CI, int MW, int NW, int NR, bool POOL, bool FUSE1A>
__global__ __launch_bounds__(MW * NW * 64, 2) void mconv5_kernel(
    const ushort* __restrict__ in, size_t ipl,
    const float* __restrict__ image, const float* __restrict__ w1a,
    const float* __restrict__ b1a,
    const ushort* __restrict__ whi, const ushort* __restrict__ wlo, // [9][COT][CI]
    const float* __restrict__ bias,
    ushort* __restrict__ out, size_t opl,
    int H, int W, int COT, int TXC,
    int iy0, int inr, int y_start, int y_lim, int oy0, int onr)
{
    constexpr int BS = MW * NW * 64;
    constexpr int HALO = (MW * 8 + 2) * 10;          // 180 for MW=2
    __shared__ __align__(16) ushort AHI[HALO * 64];
    __shared__ __align__(16) ushort ALO[HALO * 64];
    __shared__ float fshared[FUSE1A ? 880 : 4];

    int t = threadIdx.x;
    int tx = blockIdx.x % TXC, ty = blockIdx.x / TXC;
    int x0 = tx * 8, y0 = y_start + ty * (MW * 8);
    int co0 = blockIdx.y * (NW * NR * 16);
    int b = blockIdx.z;

    int lane = t & 63, wid = t >> 6;
    int wm = wid / NW, wn = wid % NW;
    int fr = lane & 15, fg = lane >> 4;

    int hpx[4];
    #pragma unroll
    for (int mi = 0; mi < 4; ++mi) {
        int p = wm * 64 + mi * 16 + fr;
        hpx[mi] = (p >> 3) * 10 + (p & 7);
    }
    size_t wro[NR];
    #pragma unroll
    for (int nj = 0; nj < NR; ++nj) {
        int cog = co0 + wn * NR * 16 + nj * 16 + fr;
        wro[nj] = (size_t)cog * CI + fg * 8;
    }

    f32x4 acc[4][NR];
    #pragma unroll
    for (int nj = 0; nj < NR; ++nj) {
        float bv = bias[co0 + wn * NR * 16 + nj * 16 + fr];
        #pragma unroll
        for (int mi = 0; mi < 4; ++mi)
            acc[mi][nj] = f32x4{bv, bv, bv, bv};
    }

    const int NC = CI / 64;
    for (int cc = 0; cc < NC; ++cc) {
        if (cc > 0) __syncthreads();
        // ---- stage A chunk (HALO px x 64 ch, hi+lo, swizzled) ----
        if constexpr (FUSE1A) {
            float* img_s = fshared;          // (MW*8+4) x 12 = 240 for MW=2
            float* w1a_s = fshared + 240;    // 576
            float* b1a_s = fshared + 816;    // 64
            for (int idx = t; idx < 240; idx += BS) {
                int iy = idx / 12, ix = idx % 12;
                int gy = y0 - 2 + iy, gx = x0 - 2 + ix;
                img_s[idx] = (gy >= 0 && gy < H && gx >= 0 && gx < W)
                                 ? image[((size_t)b * H + gy) * W + gx] : 0.f;
            }
            for (int idx = t; idx < 576; idx += BS) w1a_s[idx] = w1a[idx];
            if (t < 64) b1a_s[t] = b1a[t];
            __syncthreads();
            for (int idx = t; idx < HALO * 64; idx += BS) {
                int hp = idx >> 6, c = idx & 63;
                int hpy = hp / 10, hpx2 = hp % 10;
                int gy = y0 - 1 + hpy, gx = x0 - 1 + hpx2;
                float v = 0.f;
                if (gy >= 0 && gy < H && gx >= 0 && gx < W) {
                    float s = b1a_s[c];
                    #pragma unroll
                    for (int ky = 0; ky < 3; ++ky)
                        #pragma unroll
                        for (int kx = 0; kx < 3; ++kx)
                            s = fmaf(img_s[(hpy + ky) * 12 + hpx2 + kx],
                                     w1a_s[c * 9 + ky * 3 + kx], s);
                    v = fmaxf(s, 0.f);
                }
                ushort h, l; f32_split(v, h, l);
                int base = hp * 64 + ((((c >> 3) ^ (hp & 7))) << 3) + (c & 7);
                AHI[base] = h;
                ALO[base] = l;
            }
        } else {
            for (int idx = t; idx < HALO * 8; idx += BS) {
                int hp = idx >> 3, c8 = idx & 7;
                int hy = y0 - 1 + hp / 10, hx = x0 - 1 + hp % 10;
                int4 vh = make_int4(0, 0, 0, 0), vl = make_int4(0, 0, 0, 0);
                if (hy >= iy0 && hy < iy0 + inr && hx >= 0 && hx < W) {
                    size_t a = (((size_t)b * inr + (hy - iy0)) * W + hx) * CI + cc * 64 + c8 * 8;
                    vh = *reinterpret_cast<const int4*>(&in[a]);
                    vl = *reinterpret_cast<const int4*>(&in[a + ipl]);
                }
                int base = hp * 64 + ((c8 ^ (hp & 7)) << 3);
                *reinterpret_cast<int4*>(&AHI[base]) = vh;
                *reinterpret_cast<int4*>(&ALO[base]) = vl;
            }
        }

        size_t ccoff = (size_t)cc * 64;
        f16x8 whA[NR], wlA[NR], whB[NR], wlB[NR];
        // preload tap 0, kc 0 (drains with staging loads at the barrier)
        {
            const ushort* wtH = whi + ccoff;
            const ushort* wtL = wlo + ccoff;
            #pragma unroll
            for (int nj = 0; nj < NR; ++nj) {
                whA[nj] = *reinterpret_cast<const f16x8*>(&wtH[wro[nj]]);
                wlA[nj] = *reinterpret_cast<const f16x8*>(&wtL[wro[nj]]);
            }
        }
        __syncthreads();

        // ---- K-loop: 9 taps x 2 kc, weight loads double-buffered ----
        #pragma unroll 1
        for (int tap = 0; tap < 9; ++tap) {
            // prefetch this tap's kc=1 weights into B
            {
                const ushort* wtH = whi + (size_t)tap * COT * CI + ccoff + 32;
                const ushort* wtL = wlo + (size_t)tap * COT * CI + ccoff + 32;
                #pragma unroll
                for (int nj = 0; nj < NR; ++nj) {
                    whB[nj] = *reinterpret_cast<const f16x8*>(&wtH[wro[nj]]);
                    wlB[nj] = *reinterpret_cast<const f16x8*>(&wtL[wro[nj]]);
                }
            }
            int ky = tap / 3, kx = tap - ky * 3;
            // compute kc=0 with A-buffer
            {
                f16x8 ah[4], al[4];
                #pragma unroll
                for (int mi = 0; mi < 4; ++mi) {
                    int hp = hpx[mi] + ky * 10 + kx;
                    int slot = fg ^ (hp & 7);
                    ah[mi] = *reinterpret_cast<const f16x8*>(&AHI[hp * 64 + slot * 8]);
                    al[mi] = *reinterpret_cast<const f16x8*>(&ALO[hp * 64 + slot * 8]);
                }
                #pragma unroll
                for (int mi = 0; mi < 4; ++mi)
                    #pragma unroll
                    for (int nj = 0; nj < NR; ++nj) {
                        acc[mi][nj] = __builtin_amdgcn_mfma_f32_16x16x32_f16(
                            ah[mi], whA[nj], acc[mi][nj], 0, 0, 0);
                        acc[mi][nj] = __builtin_amdgcn_mfma_f32_16x16x32_f16(
                            al[mi], whA[nj], acc[mi][nj], 0, 0, 0);
                        acc[mi][nj] = __builtin_amdgcn_mfma_f32_16x16x32_f16(
                            ah[mi], wlA[nj], acc[mi][nj], 0, 0, 0);
                    }
            }
            // prefetch next tap's kc=0 weights into A
            if (tap < 8) {
                const ushort* wtH = whi + (size_t)(tap + 1) * COT * CI + ccoff;
                const ushort* wtL = wlo + (size_t)(tap + 1) * COT * CI + ccoff;
                #pragma unroll
                for (int nj = 0; nj < NR; ++nj) {
                    whA[nj] = *reinterpret_cast<const f16x8*>(&wtH[wro[nj]]);
                    wlA[nj] = *reinterpret_cast<const f16x8*>(&wtL[wro[nj]]);
                }
            }
            // compute kc=1 with B-buffer
            {
                f16x8 ah[4], al[4];
                #pragma unroll
                for (int mi = 0; mi < 4; ++mi) {
                    int hp = hpx[mi] + ky * 10 + kx;
                    int slot = (4 + fg) ^ (hp & 7);
                    ah[mi] = *reinterpret_cast<const f16x8*>(&AHI[hp * 64 + slot * 8]);
                    al[mi] = *reinterpret_cast<const f16x8*>(&ALO[hp * 64 + slot * 8]);
                }
                #pragma unroll
                for (int mi = 0; mi < 4; ++mi)
                    #pragma unroll
                    for (int nj = 0; nj < NR; ++nj) {
                        acc[mi][nj] = __builtin_amdgcn_mfma_f32_16x16x32_f16(
                            ah[mi], whB[nj], acc[mi][nj], 0, 0, 0);
                        acc[mi][nj] = __builtin_amdgcn_mfma_f32_16x16x32_f16(
                            al[mi], whB[nj], acc[mi][nj], 0, 0, 0);
                        acc[mi][nj] = __builtin_amdgcn_mfma_f32_16x16x32_f16(
                            ah[mi], wlB[nj], acc[mi][nj], 0, 0, 0);
                    }
            }
        }
    }

    // ---- epilogue ----
    if constexpr (POOL) {
        // px: y = wm*8+mi*2+(fg>>1), x = (fg&1)*4+r. pairs: x^1=r^1, y^1=fg^2(lane^32)
        int Wp = W >> 1;
        #pragma unroll
        for (int mi = 0; mi < 4; ++mi) {
            int qy = (y0 >> 1) + wm * 4 + mi;
            #pragma unroll
            for (int nj = 0; nj < NR; ++nj) {
                f32x4 v = acc[mi][nj];
                float v0 = fmaxf(v[0], 0.f), v1 = fmaxf(v[1], 0.f);
                float v2 = fmaxf(v[2], 0.f), v3 = fmaxf(v[3], 0.f);
                float mA = fmaxf(v0, v1), mB = fmaxf(v2, v3);
                float pA = fmaxf(mA, __shfl_xor(mA, 32));
                float pB = fmaxf(mB, __shfl_xor(mB, 32));
                if ((fg & 2) == 0 && qy < y_lim) {
                    int qx = (x0 >> 1) + (fg & 1) * 2;
                    int cog = co0 + wn * NR * 16 + nj * 16 + fr;
                    size_t oa = (((size_t)b * onr + (qy - oy0)) * Wp + qx) * COT + cog;
                    ushort h, l;
                    f32_split(pA, h, l);
                    out[oa] = h; out[oa + opl] = l;
                    f32_split(pB, h, l);
                    out[oa + COT] = h; out[oa + COT + opl] = l;
                }
            }
        }
    } else {
        #pragma unroll
        for (int mi = 0; mi < 4; ++mi)
            #pragma unroll
            for (int r = 0; r < 4; ++r) {
                int gy = y0 + wm * 8 + mi * 2 + (fg >> 1);
                int gx = x0 + (fg & 1) * 4 + r;
                if (gy < y_lim) {
                    size_t base = (((size_t)b * onr + (gy - oy0)) * W + gx) * COT;
                    #pragma unroll
                    for (int nj = 0; nj < NR; ++nj) {
                        int cog = co0 + wn * NR * 16 + nj * 16 + fr;
                        ushort h, l;
                        f32_split(fmaxf(acc[mi][nj][r], 0.f), h, l);
                        out[base + cog] = h;
                        out[base + cog + opl] = l;
                    }
                }
            }
    }
}

// ---------------------------------------------------------------------------
// Detector head: 1x1 conv (256->65) + softmax(65) + dustbin drop + pixel
// shuffle to [8,480,640]. cpa = f16 hi/lo planes [38400][256]. Wave per pixel.
// ---------------------------------------------------------------------------
__global__ __launch_bounds__(256) void scores_kernel(
    const ushort* __restrict__ cpa, size_t cpl, const float* __restrict__ wpb,
    const float* __restrict__ bpb, float* __restrict__ sc)
{
    __shared__ __align__(16) float wT[128][66];
    __shared__ __align__(16) float xs[4][256];
    int t = threadIdx.x;
    int wave = t >> 6, lane = t & 63;
    int p = blockIdx.x * 4 + wave;

    ushort4 xh = *reinterpret_cast<const ushort4*>(&cpa[(size_t)p * 256 + lane * 4]);
    ushort4 xl = *reinterpret_cast<const ushort4*>(&cpa[(size_t)p * 256 + lane * 4 + cpl]);
    xs[wave][lane * 4 + 0] = h2f(xh.x) + h2f(xl.x);
    xs[wave][lane * 4 + 1] = h2f(xh.y) + h2f(xl.y);
    xs[wave][lane * 4 + 2] = h2f(xh.z) + h2f(xl.z);
    xs[wave][lane * 4 + 3] = h2f(xh.w) + h2f(xl.w);

    float a = bpb[lane];
    float a2 = bpb[64];
    for (int k0 = 0; k0 < 256; k0 += 128) {
        __syncthreads();
        for (int idx = t; idx < 65 * 128; idx += 256) {
            int o = idx / 128, i = idx % 128;
            wT[i][o] = wpb[o * 256 + k0 + i];
        }
        __syncthreads();
        for (int i = 0; i < 128; ++i) {
            float xb = xs[wave][k0 + i];
            a  = fmaf(xb, wT[i][lane], a);
            a2 = fmaf(xb, wT[i][64], a2);
        }
    }
    float m = a;
    #pragma unroll
    for (int off = 32; off; off >>= 1) m = fmaxf(m, __shfl_xor(m, off));
    m = fmaxf(m, a2);
    float e = expf(a - m);
    float s = e;
    #pragma unroll
    for (int off = 32; off; off >>= 1) s += __shfl_xor(s, off);
    s += expf(a2 - m);
    float r = e / s;
    int b = p / 4800, hw = p % 4800, h = hw / 80, w = hw % 80;
    int rr = lane >> 3, cc = lane & 7;
    sc[b * 307200 + (h * 8 + rr) * 640 + (w * 8 + cc)] = r;
}

// ---------------------------------------------------------------------------
// NMS: 16x16 tile + radius-3 halo, 7x7 max with -inf padding. (fp32)
// ---------------------------------------------------------------------------
#define NMS_STAGE(SRC)                                                        \
    __shared__ float ts[22][23];                                              \
    const int H = 480, W = 640;                                               \
    int bx = blockIdx.x * 16, by = blockIdx.y * 16, b = blockIdx.z;           \
    int t = threadIdx.x;                                                      \
    for (int idx = t; idx < 22 * 22; idx += 256) {                            \
        int yy = idx / 22, xx = idx % 22;                                     \
        int gy = by + yy - 3, gx = bx + xx - 3;                               \
        ts[yy][xx] = (gy >= 0 && gy < H && gx >= 0 && gx < W)                 \
                         ? (SRC)[b * 307200 + gy * W + gx] : -INFINITY;       \
    }                                                                         \
    __syncthreads();                                                          \
    int lx = t & 15, ly = t >> 4;                                             \
    float mx = -INFINITY;                                                     \
    _Pragma("unroll")                                                         \
    for (int dy = 0; dy < 7; ++dy)                                            \
        _Pragma("unroll")                                                     \
        for (int dx = 0; dx < 7; ++dx)                                       \
            mx = fmaxf(mx, ts[ly + dy][lx + dx]);                            \
    int p = b * 307200 + (by + ly) * W + (bx + lx);

__global__ __launch_bounds__(256) void nms_max_mask(
    const float* __restrict__ s, float* __restrict__ M)
{
    NMS_STAGE(s)
    M[p] = (ts[ly + 3][lx + 3] == mx) ? 1.f : 0.f;
}

__global__ __launch_bounds__(256) void nms_supp(
    const float* __restrict__ M, const float* __restrict__ s,
    float* __restrict__ supp, float* __restrict__ ss)
{
    NMS_STAGE(M)
    float sup = (mx > 0.f) ? 1.f : 0.f;
    supp[p] = sup;
    ss[p] = (sup > 0.f) ? 0.f : s[p];
}

template<bool LAST>
__global__ __launch_bounds__(256) void nms_update(
    const float* __restrict__ ssb, const float* __restrict__ supp,
    const float* __restrict__ s, float* __restrict__ M, float* __restrict__ outp)
{
    NMS_STAGE(ssb)
    bool new_max = (ts[ly + 3][lx + 3] == mx);
    float mo = M[p];
    float sp = supp[p];
    bool mn = (mo > 0.f) || (new_max && sp == 0.f);
    if (LAST)
        outp[p] = mn ? s[p] : 0.f;
    else
        M[p] = mn ? 1.f : 0.f;
}

// ---------------------------------------------------------------------------
// Descriptor head: 1x1 conv (256->256) + bias + per-pixel L2 normalize.
// f16 hi/lo NHWC input [38400][256] -> NCHW fp32 output [8][256][4800].
// ---------------------------------------------------------------------------
__global__ __launch_bounds__(256, 2) void descdb_kernel(
    const ushort* __restrict__ cda, size_t cpl, const float* __restrict__ wdb,
    const float* __restrict__ bdb, float* __restrict__ outp)
{
    __shared__ __align__(16) float Xs[16][65];
    __shared__ __align__(16) float Ws[16][257];
    int t = threadIdx.x;
    int m0 = blockIdx.x * 64;
    int n_id = t & 31, m_id = t >> 5;

    float acc[8][8];
    #pragma unroll
    for (int nn = 0; nn < 8; ++nn) {
        float bv = bdb[n_id + 32 * nn];
        #pragma unroll
        for (int mm = 0; mm < 8; ++mm) acc[mm][nn] = bv;
    }

    for (int k0 = 0; k0 < 256; k0 += 16) {
        __syncthreads();
        for (int idx = t; idx < 64 * 16; idx += 256) {
            int m = idx / 16, k = idx % 16;
            size_t a = (size_t)(m0 + m) * 256 + k0 + k;
            Xs[k][m] = h2f(cda[a]) + h2f(cda[a + cpl]);
        }
        for (int idx = t; idx < 256 * 16; idx += 256) {
            int o = idx / 16, k = idx % 16;
            Ws[k][o] = wdb[o * 256 + k0 + k];
        }
        __syncthreads();
        #pragma unroll
        for (int k = 0; k < 16; ++k) {
            float xv[8], wv[8];
            #pragma unroll
            for (int mm = 0; mm < 8; ++mm) xv[mm] = Xs[k][m_id * 8 + mm];
            #pragma unroll
            for (int nn = 0; nn < 8; ++nn) wv[nn] = Ws[k][n_id + 32 * nn];
            #pragma unroll
            for (int mm = 0; mm < 8; ++mm)
                #pragma unroll
                for (int nn = 0; nn < 8; ++nn)
                    acc[mm][nn] = fmaf(xv[mm], wv[nn], acc[mm][nn]);
        }
    }
    #pragma unroll
    for (int mm = 0; mm < 8; ++mm) {
        float sq = 0.f;
        #pragma unroll
        for (int nn = 0; nn < 8; ++nn) sq = fmaf(acc[mm][nn], acc[mm][nn], sq);
        #pragma unroll
        for (int off = 16; off; off >>= 1) sq += __shfl_xor(sq, off);
        float inv = 1.f / sqrtf(sq);
        int P = m0 + m_id * 8 + mm;
        int b = P / 4800, hw = P % 4800;
        #pragma unroll
        for (int nn = 0; nn < 8; ++nn) {
            int o = n_id + 32 * nn;
            outp[(b * 256 + o) * 4800 + hw] = acc[mm][nn] * inv;
        }
    }
}

// ---------------------------------------------------------------------------
extern "C" void kernel_launch(void* const* d_in, const int* in_sizes, int n_in,
                              void* d_out, int out_size, void* d_ws, size_t ws_size,
                              hipStream_t stream)
{
    const float* image = (const float*)d_in[0];
    const float* w1a = (const float*)d_in[1];  const float* b1a = (const float*)d_in[2];
    const float* w1b = (const float*)d_in[3];  const float* b1b = (const float*)d_in[4];
    const float* w2a = (const float*)d_in[5];  const float* b2a = (const float*)d_in[6];
    const float* w2b = (const float*)d_in[7];  const float* b2b = (const float*)d_in[8];
    const float* w3a = (const float*)d_in[9];  const float* b3a = (const float*)d_in[10];
    const float* w3b = (const float*)d_in[11]; const float* b3b = (const float*)d_in[12];
    const float* w4a = (const float*)d_in[13]; const float* b4a = (const float*)d_in[14];
    const float* w4b = (const float*)d_in[15]; const float* b4b = (const float*)d_in[16];
    const float* wPa = (const float*)d_in[17]; const float* bPa = (const float*)d_in[18];
    const float* wPb = (const float*)d_in[19]; const float* bPb = (const float*)d_in[20];
    const float* wDa = (const float*)d_in[21]; const float* bDa = (const float*)d_in[22];
    const float* wDb = (const float*)d_in[23]; const float* bDb = (const float*)d_in[24];

    float* out_sc   = (float*)d_out;            // [8,480,640]
    float* out_nms  = out_sc + 2457600;         // [8,480,640]
    float* out_desc = out_sc + 4915200;         // [8,256,60,80]

    ushort* U = (ushort*)d_ws;
    const int O1B = 0, O2A = 36864, O2B = 73728, O3A = 110592, O3B = 184320,
              O4A = 331776, O4B = 479232, OPA = 626688, ODA = 921600;
    const size_t TOT = 1216512;
    ushort* Whi = U;
    ushort* Wlo = U + TOT;
    ushort* A1b = U + 62000000;   // conv1 out band (<=44 rows of 240-space)
    ushort* A2b = U + 76500000;   // conv2a out band (<=42 rows)
    ushort* A3  = U + 90500000;   // [8,120,160,64]  2 x 9,830,400
    ushort* A4  = U + 2500000;    // [8,120,160,128] 2 x 19,660,800
    ushort* A5  = U + 62000000;   // [8,60,80,128]   2 x 4,915,200
    ushort* A6  = U + 42000000;   // [8,60,80,128]
    ushort* A7  = U + 52000000;   // [8,60,80,128]
    ushort* cPa = U + 72000000;   // [8,60,80,256]   2 x 9,830,400
    ushort* cDa = U + 72000000;
    float* nmsMb  = (float*)(U + 92000000);
    float* nmsSup = nmsMb + 2457600;
    float* nmsSs  = nmsSup + 2457600;

    struct WE { const float* w; int off, co, ci; };
    WE WL[9] = {{w1b, O1B, 64, 64},  {w2a, O2A, 64, 64},  {w2b, O2B, 64, 64},
                {w3a, O3A, 128, 64}, {w3b, O3B, 128, 128},{w4a, O4A, 128, 128},
                {w4b, O4B, 128, 128},{wPa, OPA, 256, 128},{wDa, ODA, 256, 128}};
    for (int i = 0; i < 9; ++i) {
        int n = WL[i].co * WL[i].ci * 9;
        wtr_kernel<<<(n + 255) / 256, 256, 0, stream>>>(
            WL[i].w, Whi + WL[i].off, Wlo + WL[i].off, WL[i].co, WL[i].ci);
    }

    const size_t P3 = 9830400, P4 = 19660800, P5 = 4915200, PP = 9830400;

    // --- stage 1+2 striped (S=40 rows of conv2's 240-space, 6 stripes) ---
    for (int r0 = 0; r0 < 240; r0 += 40) {
        int r1 = r0 + 40;
        int a0 = r0 - 2 < 0 ? 0 : r0 - 2, a1 = r1 + 2 > 240 ? 240 : r1 + 2;
        int anr = a1 - a0;
        size_t P1 = (size_t)8 * anr * 320 * 64;
        int ty1 = (2 * anr + 15) / 16;
        // conv1a (fused) + conv1b + pool
        mconv5_kernel<64, 2, 2, 2, true, true><<<dim3(80 * ty1, 1, 8), 256, 0, stream>>>(
            nullptr, 0, image, w1a, b1a, Whi + O1B, Wlo + O1B, b1b,
            A1b, P1, 480, 640, 64, 80, 0, 480, 2 * a0, a1, a0, anr);

        int c0 = r0 - 1 < 0 ? 0 : r0 - 1, c1 = r1 + 1 > 240 ? 240 : r1 + 1;
        int cnr = c1 - c0;
        size_t P2 = (size_t)8 * cnr * 320 * 64;
        int ty2 = (cnr + 15) / 16;
        mconv5_kernel<64, 2, 1, 4, false, false><<<dim3(40 * ty2, 1, 8), 128, 0, stream>>>(
            A1b, P1, nullptr, nullptr, nullptr, Whi + O2A, Wlo + O2A, b2a,
            A2b, P2, 240, 320, 64, 40, a0, anr, c0, c1, c0, cnr);

        mconv5_kernel<64, 2, 1, 4, true, false><<<dim3(40 * 3, 1, 8), 128, 0, stream>>>(
            A2b, P2, nullptr, nullptr, nullptr, Whi + O2B, Wlo + O2B, b2b,
            A3, P3, 240, 320, 64, 40, c0, cnr, r0, r1 >> 1, 0, 120);
    }

    // --- stage 3 (full) ---
    mconv5_kernel<64, 2, 2, 4, false, false><<<dim3(20 * 8, 1, 8), 256, 0, stream>>>(
        A3, P3, nullptr, nullptr, nullptr, Whi + O3A, Wlo + O3A, b3a,
        A4, P4, 120, 160, 128, 20, 0, 120, 0, 120, 0, 120);
    mconv5_kernel<128, 2, 2, 4, true, false><<<dim3(20 * 8, 1, 8), 256, 0, stream>>>(
        A4, P4, nullptr, nullptr, nullptr, Whi + O3B, Wlo + O3B, b3b,
        A5, P5, 120, 160, 128, 20, 0, 120, 0, 60, 0, 60);

    // --- stage 4 ---
    mconv5_kernel<128, 2, 2, 4, false, false><<<dim3(10 * 4, 1, 8), 256, 0, stream>>>(
        A5, P5, nullptr, nullptr, nullptr, Whi + O4A, Wlo + O4A, b4a,
        A6, P5, 60, 80, 128, 10, 0, 60, 0, 60, 0, 60);
    mconv5_kernel<128, 2, 2, 4, false, false><<<dim3(10 * 4, 1, 8), 256, 0, stream>>>(
        A6, P5, nullptr, nullptr, nullptr, Whi + O4B, Wlo + O4B, b4b,
        A7, P5, 60, 80, 128, 10, 0, 60, 0, 60, 0, 60);

    // --- detector head ---
    mconv5_kernel<128, 2, 2, 4, false, false><<<dim3(10 * 4, 2, 8), 256, 0, stream>>>(
        A7, P5, nullptr, nullptr, nullptr, Whi + OPA, Wlo + OPA, bPa,
        cPa, PP, 60, 80, 256, 10, 0, 60, 0, 60, 0, 60);
    scores_kernel<<<9600, 256, 0, stream>>>(cPa, PP, wPb, bPb, out_sc);

    // --- NMS (radius 3, 2 rounds) ---
    nms_max_mask<<<dim3(40, 30, 8), 256, 0, stream>>>(out_sc, nmsMb);
    nms_supp<<<dim3(40, 30, 8), 256, 0, stream>>>(nmsMb, out_sc, nmsSup, nmsSs);
    nms_update<false><<<dim3(40, 30, 8), 256, 0, stream>>>(nmsSs, nmsSup, out_sc, nmsMb, out_nms);
    nms_supp<<<dim3(40, 30, 8), 256, 0, stream>>>(nmsMb, out_sc, nmsSup, nmsSs);
    nms_update<true><<<dim3(40, 30, 8), 256, 0, stream>>>(nmsSs, nmsSup, out_sc, nmsMb, out_nms);

    // --- descriptor head ---
    mconv5_kernel<128, 2, 2, 4, false, false><<<dim3(10 * 4, 2, 8), 256, 0, stream>>>(
        A7, P5, nullptr, nullptr, nullptr, Whi + ODA, Wlo + ODA, bDa,
        cDa, PP, 60, 80, 256, 10, 0, 60, 0, 60, 0, 60);
    descdb_kernel<<<600, 256, 0, stream>>>(cDa, PP, wDb, bDb, out_desc);
}

// Round 13
// 2166.485 us; speedup vs baseline: 4.5492x; 1.2819x over previous
//
#include <hip/hip_runtime.h>
#include <math.h>

typedef __attribute__((ext_vector_type(8))) _Float16 f16x8;
typedef __attribute__((ext_vector_type(4))) float f32x4;

__device__ __forceinline__ void f32_split(float x, ushort& h, ushort& l) {
    _Float16 hh = (_Float16)x;
    float r = x - (float)hh;
    _Float16 ll = (_Float16)r;
    union { _Float16 f; ushort u; } a, b;
    a.f = hh; b.f = ll;
    h = a.u; l = b.u;
}
__device__ __forceinline__ float h2f(ushort u) {
    union { ushort u; _Float16 f; } v; v.u = u; return (float)v.f;
}

// ---------------------------------------------------------------------------
// Weight transform: fp32 OIHW [CO][CI][3][3] -> f16 hi/lo tap-major [9][CO][CI]
// ---------------------------------------------------------------------------
__global__ void wtr_kernel(const float* __restrict__ src, ushort* __restrict__ dhi,
                           ushort* __restrict__ dlo, int CO, int CI)
{
    int n = CO * CI * 9, coci = CO * CI;
    for (int idx = blockIdx.x * 256 + threadIdx.x; idx < n; idx += gridDim.x * 256) {
        int tp = idx / coci, r = idx % coci;
        int co = r / CI, ci = r % CI;
        ushort h, l;
        f32_split(src[((size_t)co * CI + ci) * 9 + tp], h, l);
        dhi[idx] = h; dlo[idx] = l;
    }
}

// ---------------------------------------------------------------------------
// Split-f16 MFMA implicit-GEMM conv3x3 + relu (+pool), v7.
// = v6 (swizzled pitch-64 LDS, per-lane L2 weights double-buffered at
// half-tap granularity) + 8-wide vectorized conv1a fused staging.
// Product = 3 MFMAs: ah*wh + al*wh + ah*wl (fp32 accumulate).
// ---------------------------------------------------------------------------
template<int CI, int MW, int NW, int NR, bool POOL, bool FUSE1A>
__global__ __launch_bounds__(MW * NW * 64, 2) void mconv5_kernel(
    const ushort* __restrict__ in, size_t ipl,
    const float* __restrict__ image, const float* __restrict__ w1a,
    const float* __restrict__ b1a,
    const ushort* __restrict__ whi, const ushort* __restrict__ wlo, // [9][COT][CI]
    const float* __restrict__ bias,
    ushort* __restrict__ out, size_t opl,
    int H, int W, int COT, int TXC,
    int iy0, int inr, int y_start, int y_lim, int oy0, int onr)
{
    constexpr int BS = MW * NW * 64;
    constexpr int HALO = (MW * 8 + 2) * 10;          // 180 for MW=2
    __shared__ __align__(16) ushort AHI[HALO * 64];
    __shared__ __align__(16) ushort ALO[HALO * 64];
    __shared__ float fshared[FUSE1A ? 880 : 4];

    int t = threadIdx.x;
    int tx = blockIdx.x % TXC, ty = blockIdx.x / TXC;
    int x0 = tx * 8, y0 = y_start + ty * (MW * 8);
    int co0 = blockIdx.y * (NW * NR * 16);
    int b = blockIdx.z;

    int lane = t & 63, wid = t >> 6;
    int wm = wid / NW, wn = wid % NW;
    int fr = lane & 15, fg = lane >> 4;

    int hpx[4];
    #pragma unroll
    for (int mi = 0; mi < 4; ++mi) {
        int p = wm * 64 + mi * 16 + fr;
        hpx[mi] = (p >> 3) * 10 + (p & 7);
    }
    size_t wro[NR];
    #pragma unroll
    for (int nj = 0; nj < NR; ++nj) {
        int cog = co0 + wn * NR * 16 + nj * 16 + fr;
        wro[nj] = (size_t)cog * CI + fg * 8;
    }

    f32x4 acc[4][NR];
    #pragma unroll
    for (int nj = 0; nj < NR; ++nj) {
        float bv = bias[co0 + wn * NR * 16 + nj * 16 + fr];
        #pragma unroll
        for (int mi = 0; mi < 4; ++mi)
            acc[mi][nj] = f32x4{bv, bv, bv, bv};
    }

    const int NC = CI / 64;
    for (int cc = 0; cc < NC; ++cc) {
        if (cc > 0) __syncthreads();
        // ---- stage A chunk (HALO px x 64 ch, hi+lo, swizzled) ----
        if constexpr (FUSE1A) {
            float* img_s = fshared;          // (MW*8+4) x 12 = 240 for MW=2
            float* w1a_s = fshared + 240;    // 576
            float* b1a_s = fshared + 816;    // 64
            for (int idx = t; idx < 240; idx += BS) {
                int iy = idx / 12, ix = idx % 12;
                int gy = y0 - 2 + iy, gx = x0 - 2 + ix;
                img_s[idx] = (gy >= 0 && gy < H && gx >= 0 && gx < W)
                                 ? image[((size_t)b * H + gy) * W + gx] : 0.f;
            }
            for (int idx = t; idx < 576; idx += BS) w1a_s[idx] = w1a[idx];
            if (t < 64) b1a_s[t] = b1a[t];
            __syncthreads();
            // 8-channel-vectorized conv1a: one (px, 8ch-group) per iteration
            for (int idx = t; idx < HALO * 8; idx += BS) {
                int hp = idx >> 3, g = idx & 7;
                int hpy = hp / 10, hpx2 = hp - hpy * 10;
                int gy = y0 - 1 + hpy, gx = x0 - 1 + hpx2;
                union { ushort u[8]; int4 v; } hu, lu;
                if (gy >= 0 && gy < H && gx >= 0 && gx < W) {
                    float iv[9];
                    #pragma unroll
                    for (int ky = 0; ky < 3; ++ky)
                        #pragma unroll
                        for (int kx = 0; kx < 3; ++kx)
                            iv[ky * 3 + kx] = img_s[(hpy + ky) * 12 + hpx2 + kx];
                    #pragma unroll
                    for (int j = 0; j < 8; ++j) {
                        int c = g * 8 + j;
                        float s = b1a_s[c];
                        const float* wc = &w1a_s[c * 9];
                        #pragma unroll
                        for (int k = 0; k < 9; ++k) s = fmaf(iv[k], wc[k], s);
                        f32_split(fmaxf(s, 0.f), hu.u[j], lu.u[j]);
                    }
                } else {
                    hu.v = make_int4(0, 0, 0, 0);
                    lu.v = make_int4(0, 0, 0, 0);
                }
                int base = hp * 64 + ((g ^ (hp & 7)) << 3);
                *reinterpret_cast<int4*>(&AHI[base]) = hu.v;
                *reinterpret_cast<int4*>(&ALO[base]) = lu.v;
            }
        } else {
            for (int idx = t; idx < HALO * 8; idx += BS) {
                int hp = idx >> 3, c8 = idx & 7;
                int hy = y0 - 1 + hp / 10, hx = x0 - 1 + hp % 10;
                int4 vh = make_int4(0, 0, 0, 0), vl = make_int4(0, 0, 0, 0);
                if (hy >= iy0 && hy < iy0 + inr && hx >= 0 && hx < W) {
                    size_t a = (((size_t)b * inr + (hy - iy0)) * W + hx) * CI + cc * 64 + c8 * 8;
                    vh = *reinterpret_cast<const int4*>(&in[a]);
                    vl = *reinterpret_cast<const int4*>(&in[a + ipl]);
                }
                int base = hp * 64 + ((c8 ^ (hp & 7)) << 3);
                *reinterpret_cast<int4*>(&AHI[base]) = vh;
                *reinterpret_cast<int4*>(&ALO[base]) = vl;
            }
        }

        size_t ccoff = (size_t)cc * 64;
        f16x8 whA[NR], wlA[NR], whB[NR], wlB[NR];
        // preload tap 0, kc 0 (drains with staging loads at the barrier)
        {
            const ushort* wtH = whi + ccoff;
            const ushort* wtL = wlo + ccoff;
            #pragma unroll
            for (int nj = 0; nj < NR; ++nj) {
                whA[nj] = *reinterpret_cast<const f16x8*>(&wtH[wro[nj]]);
                wlA[nj] = *reinterpret_cast<const f16x8*>(&wtL[wro[nj]]);
            }
        }
        __syncthreads();

        // ---- K-loop: 9 taps x 2 kc, weight loads double-buffered ----
        #pragma unroll 1
        for (int tap = 0; tap < 9; ++tap) {
            // prefetch this tap's kc=1 weights into B
            {
                const ushort* wtH = whi + (size_t)tap * COT * CI + ccoff + 32;
                const ushort* wtL = wlo + (size_t)tap * COT * CI + ccoff + 32;
                #pragma unroll
                for (int nj = 0; nj < NR; ++nj) {
                    whB[nj] = *reinterpret_cast<const f16x8*>(&wtH[wro[nj]]);
                    wlB[nj] = *reinterpret_cast<const f16x8*>(&wtL[wro[nj]]);
                }
            }
            int ky = tap / 3, kx = tap - ky * 3;
            // compute kc=0 with A-buffer
            {
                f16x8 ah[4], al[4];
                #pragma unroll
                for (int mi = 0; mi < 4; ++mi) {
                    int hp = hpx[mi] + ky * 10 + kx;
                    int slot = fg ^ (hp & 7);
                    ah[mi] = *reinterpret_cast<const f16x8*>(&AHI[hp * 64 + slot * 8]);
                    al[mi] = *reinterpret_cast<const f16x8*>(&ALO[hp * 64 + slot * 8]);
                }
                #pragma unroll
                for (int mi = 0; mi < 4; ++mi)
                    #pragma unroll
                    for (int nj = 0; nj < NR; ++nj) {
                        acc[mi][nj] = __builtin_amdgcn_mfma_f32_16x16x32_f16(
                            ah[mi], whA[nj], acc[mi][nj], 0, 0, 0);
                        acc[mi][nj] = __builtin_amdgcn_mfma_f32_16x16x32_f16(
                            al[mi], whA[nj], acc[mi][nj], 0, 0, 0);
                        acc[mi][nj] = __builtin_amdgcn_mfma_f32_16x16x32_f16(
                            ah[mi], wlA[nj], acc[mi][nj], 0, 0, 0);
                    }
            }
            // prefetch next tap's kc=0 weights into A
            if (tap < 8) {
                const ushort* wtH = whi + (size_t)(tap + 1) * COT * CI + ccoff;
                const ushort* wtL = wlo + (size_t)(tap + 1) * COT * CI + ccoff;
                #pragma unroll
                for (int nj = 0; nj < NR; ++nj) {
                    whA[nj] = *reinterpret_cast<const f16x8*>(&wtH[wro[nj]]);
                    wlA[nj] = *reinterpret_cast<const f16x8*>(&wtL[wro[nj]]);
                }
            }
            // compute kc=1 with B-buffer
            {
                f16x8 ah[4], al[4];
                #pragma unroll
                for (int mi = 0; mi < 4; ++mi) {
                    int hp = hpx[mi] + ky * 10 + kx;
                    int slot = (4 + fg) ^ (hp & 7);
                    ah[mi] = *reinterpret_cast<const f16x8*>(&AHI[hp * 64 + slot * 8]);
                    al[mi] = *reinterpret_cast<const f16x8*>(&ALO[hp * 64 + slot * 8]);
                }
                #pragma unroll
                for (int mi = 0; mi < 4; ++mi)
                    #pragma unroll
                    for (int nj = 0; nj < NR; ++nj) {
                        acc[mi][nj] = __builtin_amdgcn_mfma_f32_16x16x32_f16(
                            ah[mi], whB[nj], acc[mi][nj], 0, 0, 0);
                        acc[mi][nj] = __builtin_amdgcn_mfma_f32_16x16x32_f16(
                            al[mi], whB[nj], acc[mi][nj], 0, 0, 0);
                        acc[mi][nj] = __builtin_amdgcn_mfma_f32_16x16x32_f16(
                            ah[mi], wlB[nj], acc[mi][nj], 0, 0, 0);
                    }
            }
        }
    }

    // ---- epilogue ----
    if constexpr (POOL) {
        // px: y = wm*8+mi*2+(fg>>1), x = (fg&1)*4+r. pairs: x^1=r^1, y^1=fg^2(lane^32)
        int Wp = W >> 1;
        #pragma unroll
        for (int mi = 0; mi < 4; ++mi) {
            int qy = (y0 >> 1) + wm * 4 + mi;
            #pragma unroll
            for (int nj = 0; nj < NR; ++nj) {
                f32x4 v = acc[mi][nj];
                float v0 = fmaxf(v[0], 0.f), v1 = fmaxf(v[1], 0.f);
                float v2 = fmaxf(v[2], 0.f), v3 = fmaxf(v[3], 0.f);
                float mA = fmaxf(v0, v1), mB = fmaxf(v2, v3);
                float pA = fmaxf(mA, __shfl_xor(mA, 32));
                float pB = fmaxf(mB, __shfl_xor(mB, 32));
                if ((fg & 2) == 0 && qy < y_lim) {
                    int qx = (x0 >> 1) + (fg & 1) * 2;
                    int cog = co0 + wn * NR * 16 + nj * 16 + fr;
                    size_t oa = (((size_t)b * onr + (qy - oy0)) * Wp + qx) * COT + cog;
                    ushort h, l;
                    f32_split(pA, h, l);
                    out[oa] = h; out[oa + opl] = l;
                    f32_split(pB, h, l);
                    out[oa + COT] = h; out[oa + COT + opl] = l;
                }
            }
        }
    } else {
        #pragma unroll
        for (int mi = 0; mi < 4; ++mi)
            #pragma unroll
            for (int r = 0; r < 4; ++r) {
                int gy = y0 + wm * 8 + mi * 2 + (fg >> 1);
                int gx = x0 + (fg & 1) * 4 + r;
                if (gy < y_lim) {
                    size_t base = (((size_t)b * onr + (gy - oy0)) * W + gx) * COT;
                    #pragma unroll
                    for (int nj = 0; nj < NR; ++nj) {
                        int cog = co0 + wn * NR * 16 + nj * 16 + fr;
                        ushort h, l;
                        f32_split(fmaxf(acc[mi][nj][r], 0.f), h, l);
                        out[base + cog] = h;
                        out[base + cog + opl] = l;
                    }
                }
            }
    }
}

// ---------------------------------------------------------------------------
// Detector head: 1x1 conv (256->65) + softmax(65) + dustbin drop + pixel
// shuffle to [8,480,640]. cpa = f16 hi/lo planes [38400][256]. Wave per pixel.
// ---------------------------------------------------------------------------
__global__ __launch_bounds__(256) void scores_kernel(
    const ushort* __restrict__ cpa, size_t cpl, const float* __restrict__ wpb,
    const float* __restrict__ bpb, float* __restrict__ sc)
{
    __shared__ __align__(16) float wT[128][66];
    __shared__ __align__(16) float xs[4][256];
    int t = threadIdx.x;
    int wave = t >> 6, lane = t & 63;
    int p = blockIdx.x * 4 + wave;

    ushort4 xh = *reinterpret_cast<const ushort4*>(&cpa[(size_t)p * 256 + lane * 4]);
    ushort4 xl = *reinterpret_cast<const ushort4*>(&cpa[(size_t)p * 256 + lane * 4 + cpl]);
    xs[wave][lane * 4 + 0] = h2f(xh.x) + h2f(xl.x);
    xs[wave][lane * 4 + 1] = h2f(xh.y) + h2f(xl.y);
    xs[wave][lane * 4 + 2] = h2f(xh.z) + h2f(xl.z);
    xs[wave][lane * 4 + 3] = h2f(xh.w) + h2f(xl.w);

    float a = bpb[lane];
    float a2 = bpb[64];
    for (int k0 = 0; k0 < 256; k0 += 128) {
        __syncthreads();
        for (int idx = t; idx < 65 * 128; idx += 256) {
            int o = idx / 128, i = idx % 128;
            wT[i][o] = wpb[o * 256 + k0 + i];
        }
        __syncthreads();
        for (int i = 0; i < 128; ++i) {
            float xb = xs[wave][k0 + i];
            a  = fmaf(xb, wT[i][lane], a);
            a2 = fmaf(xb, wT[i][64], a2);
        }
    }
    float m = a;
    #pragma unroll
    for (int off = 32; off; off >>= 1) m = fmaxf(m, __shfl_xor(m, off));
    m = fmaxf(m, a2);
    float e = expf(a - m);
    float s = e;
    #pragma unroll
    for (int off = 32; off; off >>= 1) s += __shfl_xor(s, off);
    s += expf(a2 - m);
    float r = e / s;
    int b = p / 4800, hw = p % 4800, h = hw / 80, w = hw % 80;
    int rr = lane >> 3, cc = lane & 7;
    sc[b * 307200 + (h * 8 + rr) * 640 + (w * 8 + cc)] = r;
}

// ---------------------------------------------------------------------------
// NMS: 16x16 tile + radius-3 halo, 7x7 max with -inf padding. (fp32)
// ---------------------------------------------------------------------------
#define NMS_STAGE(SRC)                                                        \
    __shared__ float ts[22][23];                                              \
    const int H = 480, W = 640;                                               \
    int bx = blockIdx.x * 16, by = blockIdx.y * 16, b = blockIdx.z;           \
    int t = threadIdx.x;                                                      \
    for (int idx = t; idx < 22 * 22; idx += 256) {                            \
        int yy = idx / 22, xx = idx % 22;                                     \
        int gy = by + yy - 3, gx = bx + xx - 3;                               \
        ts[yy][xx] = (gy >= 0 && gy < H && gx >= 0 && gx < W)                 \
                         ? (SRC)[b * 307200 + gy * W + gx] : -INFINITY;       \
    }                                                                         \
    __syncthreads();                                                          \
    int lx = t & 15, ly = t >> 4;                                             \
    float mx = -INFINITY;                                                     \
    _Pragma("unroll")                                                         \
    for (int dy = 0; dy < 7; ++dy)                                            \
        _Pragma("unroll")                                                     \
        for (int dx = 0; dx < 7; ++dx)                                       \
            mx = fmaxf(mx, ts[ly + dy][lx + dx]);                            \
    int p = b * 307200 + (by + ly) * W + (bx + lx);

__global__ __launch_bounds__(256) void nms_max_mask(
    const float* __restrict__ s, float* __restrict__ M)
{
    NMS_STAGE(s)
    M[p] = (ts[ly + 3][lx + 3] == mx) ? 1.f : 0.f;
}

__global__ __launch_bounds__(256) void nms_supp(
    const float* __restrict__ M, const float* __restrict__ s,
    float* __restrict__ supp, float* __restrict__ ss)
{
    NMS_STAGE(M)
    float sup = (mx > 0.f) ? 1.f : 0.f;
    supp[p] = sup;
    ss[p] = (sup > 0.f) ? 0.f : s[p];
}

template<bool LAST>
__global__ __launch_bounds__(256) void nms_update(
    const float* __restrict__ ssb, const float* __restrict__ supp,
    const float* __restrict__ s, float* __restrict__ M, float* __restrict__ outp)
{
    NMS_STAGE(ssb)
    bool new_max = (ts[ly + 3][lx + 3] == mx);
    float mo = M[p];
    float sp = supp[p];
    bool mn = (mo > 0.f) || (new_max && sp == 0.f);
    if (LAST)
        outp[p] = mn ? s[p] : 0.f;
    else
        M[p] = mn ? 1.f : 0.f;
}

// ---------------------------------------------------------------------------
// Descriptor head: 1x1 conv (256->256) + bias + per-pixel L2 normalize.
// f16 hi/lo NHWC input [38400][256] -> NCHW fp32 output [8][256][4800].
// ---------------------------------------------------------------------------
__global__ __launch_bounds__(256, 2) void descdb_kernel(
    const ushort* __restrict__ cda, size_t cpl, const float* __restrict__ wdb,
    const float* __restrict__ bdb, float* __restrict__ outp)
{
    __shared__ __align__(16) float Xs[16][65];
    __shared__ __align__(16) float Ws[16][257];
    int t = threadIdx.x;
    int m0 = blockIdx.x * 64;
    int n_id = t & 31, m_id = t >> 5;

    float acc[8][8];
    #pragma unroll
    for (int nn = 0; nn < 8; ++nn) {
        float bv = bdb[n_id + 32 * nn];
        #pragma unroll
        for (int mm = 0; mm < 8; ++mm) acc[mm][nn] = bv;
    }

    for (int k0 = 0; k0 < 256; k0 += 16) {
        __syncthreads();
        for (int idx = t; idx < 64 * 16; idx += 256) {
            int m = idx / 16, k = idx % 16;
            size_t a = (size_t)(m0 + m) * 256 + k0 + k;
            Xs[k][m] = h2f(cda[a]) + h2f(cda[a + cpl]);
        }
        for (int idx = t; idx < 256 * 16; idx += 256) {
            int o = idx / 16, k = idx % 16;
            Ws[k][o] = wdb[o * 256 + k0 + k];
        }
        __syncthreads();
        #pragma unroll
        for (int k = 0; k < 16; ++k) {
            float xv[8], wv[8];
            #pragma unroll
            for (int mm = 0; mm < 8; ++mm) xv[mm] = Xs[k][m_id * 8 + mm];
            #pragma unroll
            for (int nn = 0; nn < 8; ++nn) wv[nn] = Ws[k][n_id + 32 * nn];
            #pragma unroll
            for (int mm = 0; mm < 8; ++mm)
                #pragma unroll
                for (int nn = 0; nn < 8; ++nn)
                    acc[mm][nn] = fmaf(xv[mm], wv[nn], acc[mm][nn]);
        }
    }
    #pragma unroll
    for (int mm = 0; mm < 8; ++mm) {
        float sq = 0.f;
        #pragma unroll
        for (int nn = 0; nn < 8; ++nn) sq = fmaf(acc[mm][nn], acc[mm][nn], sq);
        #pragma unroll
        for (int off = 16; off; off >>= 1) sq += __shfl_xor(sq, off);
        float inv = 1.f / sqrtf(sq);
        int P = m0 + m_id * 8 + mm;
        int b = P / 4800, hw = P % 4800;
        #pragma unroll
        for (int nn = 0; nn < 8; ++nn) {
            int o = n_id + 32 * nn;
            outp[(b * 256 + o) * 4800 + hw] = acc[mm][nn] * inv;
        }
    }
}

// ---------------------------------------------------------------------------
extern "C" void kernel_launch(void* const* d_in, const int* in_sizes, int n_in,
                              void* d_out, int out_size, void* d_ws, size_t ws_size,
                              hipStream_t stream)
{
    const float* image = (const float*)d_in[0];
    const float* w1a = (const float*)d_in[1];  const float* b1a = (const float*)d_in[2];
    const float* w1b = (const float*)d_in[3];  const float* b1b = (const float*)d_in[4];
    const float* w2a = (const float*)d_in[5];  const float* b2a = (const float*)d_in[6];
    const float* w2b = (const float*)d_in[7];  const float* b2b = (const float*)d_in[8];
    const float* w3a = (const float*)d_in[9];  const float* b3a = (const float*)d_in[10];
    const float* w3b = (const float*)d_in[11]; const float* b3b = (const float*)d_in[12];
    const float* w4a = (const float*)d_in[13]; const float* b4a = (const float*)d_in[14];
    const float* w4b = (const float*)d_in[15]; const float* b4b = (const float*)d_in[16];
    const float* wPa = (const float*)d_in[17]; const float* bPa = (const float*)d_in[18];
    const float* wPb = (const float*)d_in[19]; const float* bPb = (const float*)d_in[20];
    const float* wDa = (const float*)d_in[21]; const float* bDa = (const float*)d_in[22];
    const float* wDb = (const float*)d_in[23]; const float* bDb = (const float*)d_in[24];

    float* out_sc   = (float*)d_out;            // [8,480,640]
    float* out_nms  = out_sc + 2457600;         // [8,480,640]
    float* out_desc = out_sc + 4915200;         // [8,256,60,80]

    ushort* U = (ushort*)d_ws;
    const int O1B = 0, O2A = 36864, O2B = 73728, O3A = 110592, O3B = 184320,
              O4A = 331776, O4B = 479232, OPA = 626688, ODA = 921600;
    const size_t TOT = 1216512;
    ushort* Whi = U;
    ushort* Wlo = U + TOT;
    // full-tensor plan (peak = end of A2 = 162.6 MB < 166.6 MB proven)
    ushort* A1  = U + 2500000;    // [8,240,320,64]  hi+lo (P1 = 39,321,600)
    ushort* A2  = U + 42000000;   // [8,240,320,64]  hi+lo
    ushort* A3  = U + 2500000;    // [8,120,160,64]  hi+lo (A1 dead)
    ushort* A4  = U + 42000000;   // [8,120,160,128] hi+lo (A2 dead)
    ushort* A5  = U + 2500000;    // [8,60,80,128]   hi+lo (A3 dead)
    ushort* A6  = U + 13000000;   // [8,60,80,128]
    ushort* A7  = U + 23000000;   // [8,60,80,128]
    ushort* cPa = U + 33000000;   // [8,60,80,256]   hi+lo (A4 dead)
    ushort* cDa = U + 33000000;
    float* nmsMb  = (float*)(U + 54000000);
    float* nmsSup = nmsMb + 2457600;
    float* nmsSs  = nmsSup + 2457600;

    struct WE { const float* w; int off, co, ci; };
    WE WL[9] = {{w1b, O1B, 64, 64},  {w2a, O2A, 64, 64},  {w2b, O2B, 64, 64},
                {w3a, O3A, 128, 64}, {w3b, O3B, 128, 128},{w4a, O4A, 128, 128},
                {w4b, O4B, 128, 128},{wPa, OPA, 256, 128},{wDa, ODA, 256, 128}};
    for (int i = 0; i < 9; ++i) {
        int n = WL[i].co * WL[i].ci * 9;
        wtr_kernel<<<(n + 255) / 256, 256, 0, stream>>>(
            WL[i].w, Whi + WL[i].off, Wlo + WL[i].off, WL[i].co, WL[i].ci);
    }

    const size_t P1 = 39321600, P2 = 39321600, P3 = 9830400,
                 P4 = 19660800, P5 = 4915200, PP = 9830400;

    // --- stage 1+2 (full tensors, no striping) ---
    // conv1a (fused) + conv1b + pool: [8,1,480,640] -> A1 [8,240,320,64]
    mconv5_kernel<64, 2, 2, 2, true, true><<<dim3(80 * 30, 1, 8), 256, 0, stream>>>(
        nullptr, 0, image, w1a, b1a, Whi + O1B, Wlo + O1B, b1b,
        A1, P1, 480, 640, 64, 80, 0, 480, 0, 240, 0, 240);
    // conv2a: A1 -> A2
    mconv5_kernel<64, 2, 1, 4, false, false><<<dim3(40 * 15, 1, 8), 128, 0, stream>>>(
        A1, P1, nullptr, nullptr, nullptr, Whi + O2A, Wlo + O2A, b2a,
        A2, P2, 240, 320, 64, 40, 0, 240, 0, 240, 0, 240);
    // conv2b + pool: A2 -> A3
    mconv5_kernel<64, 2, 1, 4, true, false><<<dim3(40 * 15, 1, 8), 128, 0, stream>>>(
        A2, P2, nullptr, nullptr, nullptr, Whi + O2B, Wlo + O2B, b2b,
        A3, P3, 240, 320, 64, 40, 0, 240, 0, 120, 0, 120);

    // --- stage 3 ---
    mconv5_kernel<64, 2, 2, 4, false, false><<<dim3(20 * 8, 1, 8), 256, 0, stream>>>(
        A3, P3, nullptr, nullptr, nullptr, Whi + O3A, Wlo + O3A, b3a,
        A4, P4, 120, 160, 128, 20, 0, 120, 0, 120, 0, 120);
    mconv5_kernel<128, 2, 2, 4, true, false><<<dim3(20 * 8, 1, 8), 256, 0, stream>>>(
        A4, P4, nullptr, nullptr, nullptr, Whi + O3B, Wlo + O3B, b3b,
        A5, P5, 120, 160, 128, 20, 0, 120, 0, 60, 0, 60);

    // --- stage 4 ---
    mconv5_kernel<128, 2, 2, 4, false, false><<<dim3(10 * 4, 1, 8), 256, 0, stream>>>(
        A5, P5, nullptr, nullptr, nullptr, Whi + O4A, Wlo + O4A, b4a,
        A6, P5, 60, 80, 128, 10, 0, 60, 0, 60, 0, 60);
    mconv5_kernel<128, 2, 2, 4, false, false><<<dim3(10 * 4, 1, 8), 256, 0, stream>>>(
        A6, P5, nullptr, nullptr, nullptr, Whi + O4B, Wlo + O4B, b4b,
        A7, P5, 60, 80, 128, 10, 0, 60, 0, 60, 0, 60);

    // --- detector head ---
    mconv5_kernel<128, 2, 2, 4, false, false><<<dim3(10 * 4, 2, 8), 256, 0, stream>>>(
        A7, P5, nullptr, nullptr, nullptr, Whi + OPA, Wlo + OPA, bPa,
        cPa, PP, 60, 80, 256, 10, 0, 60, 0, 60, 0, 60);
    scores_kernel<<<9600, 256, 0, stream>>>(cPa, PP, wPb, bPb, out_sc);

    // --- NMS (radius 3, 2 rounds) ---
    nms_max_mask<<<dim3(40, 30, 8), 256, 0, stream>>>(out_sc, nmsMb);
    nms_supp<<<dim3(40, 30, 8), 256, 0, stream>>>(nmsMb, out_sc, nmsSup, nmsSs);
    nms_update<false><<<dim3(40, 30, 8), 256, 0, stream>>>(nmsSs, nmsSup, out_sc, nmsMb, out_nms);
    nms_supp<<<dim3(40, 30, 8), 256, 0, stream>>>(nmsMb, out_sc, nmsSup, nmsSs);
    nms_update<true><<<dim3(40, 30, 8), 256, 0, stream>>>(nmsSs, nmsSup, out_sc, nmsMb, out_nms);

    // --- descriptor head ---
    mconv5_kernel<128, 2, 2, 4, false, false><<<dim3(10 * 4, 2, 8), 256, 0, stream>>>(
        A7, P5, nullptr, nullptr, nullptr, Whi + ODA, Wlo + ODA, bDa,
        cDa, PP, 60, 80, 256, 10, 0, 60, 0, 60, 0, 60);
    descdb_kernel<<<600, 256, 0, stream>>>(cDa, PP, wDb, bDb, out_desc);
}